// Round 13
// baseline (888.236 us; speedup 1.0000x reference)
//
#include <hip/hip_runtime.h>

typedef short short8 __attribute__((ext_vector_type(8)));
typedef float f32x4 __attribute__((ext_vector_type(4)));
typedef unsigned short u16x4 __attribute__((ext_vector_type(4)));

// f32 -> bf16 bits (round-to-nearest-even; finite inputs only)
__device__ __forceinline__ unsigned short f2bf(float x){
  unsigned int u = __float_as_uint(x);
  u = u + 0x7FFFu + ((u >> 16) & 1u);
  return (unsigned short)(u >> 16);
}
__device__ __forceinline__ float bf2f(unsigned short h){
  return __uint_as_float(((unsigned int)h) << 16);
}
// truncation split: hi = trunc16(x), lo = RNE(x - hi). |err| <= 2^-17 |x|.
__device__ __forceinline__ void tsplit(float x, unsigned short& h, unsigned short& l){
  unsigned int u = __float_as_uint(x);
  h = (unsigned short)(u >> 16);
  l = f2bf(x - __uint_as_float(u & 0xFFFF0000u));
}

// ---------------------------------------------------------------- weight split conv
__global__ __launch_bounds__(256) void conv2(
    const float4* __restrict__ S0, int n0, u16x4* __restrict__ D0h, u16x4* __restrict__ D0l,
    const float4* __restrict__ S1, int n1, u16x4* __restrict__ D1h, u16x4* __restrict__ D1l)
{
  int i = blockIdx.x*256 + threadIdx.x;
  const float4* S; u16x4 *Dh, *Dl;
  if (i < n0){ S = S0 + i; Dh = D0h + i; Dl = D0l + i; }
  else { i -= n0; if (i >= n1) return; S = S1 + i; Dh = D1h + i; Dl = D1l + i; }
  float4 v = *S;
  float xs[4] = {v.x, v.y, v.z, v.w};
  u16x4 h, l;
  #pragma unroll
  for (int e = 0; e < 4; ++e){ unsigned short hh, ll; tsplit(xs[e], hh, ll); h[e]=hh; l[e]=ll; }
  *Dh = h; *Dl = l;
}

// ---------------------------------------------------------------- encoder stage 1
// Also zeroes the st1 stats buffer (layer-0 LN1 accumulation target) if given.
__global__ __launch_bounds__(256) void encoder_s1(
    const float* __restrict__ xc, const float* __restrict__ yc, const float* __restrict__ xt,
    const float* __restrict__ W1, const float* __restrict__ b1,
    float* __restrict__ hid, float2* __restrict__ stz)
{
  __shared__ float zin[10];
  int blk = blockIdx.x; int b = blk>>10; int t = blk & 1023;
  int tid = threadIdx.x;
  if (stz && blk < 32) stz[blk*256 + tid] = make_float2(0.f, 0.f);
  if (tid < 10){
    float v;
    if (tid < 8)      v = (t<512) ? xc[((size_t)b*512+t)*8+tid] : xt[((size_t)b*512+(t-512))*8+tid];
    else if (tid==8)  v = (t<512) ? yc[(size_t)b*512+t] : 0.f;
    else              v = (t<512) ? 0.f : 1.f;
    zin[tid]=v;
  }
  __syncthreads();
  float s = b1[tid];
  #pragma unroll
  for (int i=0;i<10;i++) s += zin[i]*W1[i*256+tid];
  hid[(size_t)blk*256 + tid] = fmaxf(s, 0.f);
}

// ---------------------------------------------------------------- layernorm v2 (fallback paths only)
__global__ __launch_bounds__(256) void ln_v2(const float* __restrict__ z,
    const float* __restrict__ g, const float* __restrict__ be, float* __restrict__ h)
{
  const int row = blockIdx.x*4 + (threadIdx.x>>6);
  const int lane = threadIdx.x & 63;
  float4 x = *(const float4*)&z[(size_t)row*256 + lane*4];
  float s = (x.x+x.y)+(x.z+x.w);
  #pragma unroll
  for (int off=32; off; off>>=1) s += __shfl_xor(s, off);
  float mu = s * (1.f/256.f);
  float dx = x.x-mu, dy = x.y-mu, dz = x.z-mu, dw = x.w-mu;
  float v = (dx*dx+dy*dy)+(dz*dz+dw*dw);
  #pragma unroll
  for (int off=32; off; off>>=1) v += __shfl_xor(v, off);
  float r = rsqrtf(v*(1.f/256.f) + 1e-5f);
  float4 gv = *(const float4*)&g[lane*4];
  float4 bv = *(const float4*)&be[lane*4];
  float4 o;
  o.x = dx*r*gv.x + bv.x; o.y = dy*r*gv.y + bv.y;
  o.z = dz*r*gv.z + bv.z; o.w = dw*r*gv.w + bv.w;
  *(float4*)&h[(size_t)row*256 + lane*4] = o;
}

// ---------------------------------------------------------------- gemm_mfma v6
// out = EPI(LN?(A) @ B + bias). 128x128 block, 4 waves, split-bf16 MFMA.
// APRE: 0 = A f32 (trunc-split in kernel)  1 = A bf16 plane (2-term MFMA)
// BPRE: 0 = B f32 (split in kernel)        1 = B pre-split hi/lo planes (copy)
// LNA : 1 = apply LN to A during staging; stats come as PRE-ACCUMULATED
//       (sum, sumsq) per row in lnst (round-12: producers accumulate in their
//       epilogue -> the 12 ln_stats dispatches + 12x8MB zf re-reads are gone).
// EPI : 0 plain f32 ; 1 relu f32 ; 2 +resid f32 ; 3 relu -> bf16 out
// SOUT: 1 = accumulate per-row (sum, sumsq) of the OUTPUT into stout via
//       16-lane shfl reduce + atomicAdd (~4 atomics/row total).
// stzero: if non-null, blocks with blockIdx.x==0 zero stzero[m0..m0+127]
//       (slotting the zeroing into the preceding dispatch of the chain).
// Frag layouts HW-verified rounds 7-11. No launch_bounds min-waves (R4/R5).
template<int APRE, int BPRE, int EPI, int LNA, int SOUT>
__global__ __launch_bounds__(256) void gemm_mfma(
    const float* __restrict__ Af, const unsigned short* __restrict__ Ab,
    const float* __restrict__ Bf,
    const unsigned short* __restrict__ Bhg, const unsigned short* __restrict__ Blg,
    const float2* __restrict__ lnst,
    const float* __restrict__ lng, const float* __restrict__ lnb,
    const float* __restrict__ bias, const float* __restrict__ resid,
    float* __restrict__ outf, unsigned short* __restrict__ outb,
    float2* __restrict__ stout, float2* __restrict__ stzero,
    int N, int K)
{
  constexpr int LDR = 40;
  __shared__ unsigned short Ah[128*LDR];
  __shared__ unsigned short Al[(APRE==0)?(128*LDR):8];
  __shared__ unsigned short Bh[128*LDR], Bl[128*LDR];

  const int tid = threadIdx.x;
  const int lane = tid & 63, wv = tid >> 6;
  const int wm0 = (wv >> 1) * 64, wn0 = (wv & 1) * 64;
  const int m0 = blockIdx.y * 128, n0 = blockIdx.x * 128;

  if (stzero != nullptr && blockIdx.x == 0 && tid < 128)
    stzero[m0 + tid] = make_float2(0.f, 0.f);

  const int sar = tid >> 1, sak = (tid & 1) * 16;
  const int sbk = tid >> 3, sbn = (tid & 7) * 16;
  const int cA = ((sar >> 3) & 3) << 3;
  const int cB = ((sbn >> 4) & 3) << 3;

  const float* Apf = nullptr; const unsigned short* Apb = nullptr;
  if constexpr (APRE==0) Apf = Af + (size_t)(m0 + sar) * K + sak;
  else                   Apb = Ab + (size_t)(m0 + sar) * K + sak;
  const float* Bpf = nullptr; const unsigned short *Bph = nullptr, *Bpl = nullptr;
  if constexpr (BPRE==0) Bpf = Bf + (size_t)sbk * N + n0 + sbn;
  else { Bph = Bhg + (size_t)sbk * N + n0 + sbn; Bpl = Blg + (size_t)sbk * N + n0 + sbn; }

  const int rowb = lane & 15, kb = (lane >> 4) * 8;
  const int NT = K / 32;

  float mu = 0.f, rstd = 1.f;
  if constexpr (LNA==1){
    float2 st = lnst[m0 + sar];
    mu = st.x * (1.f/256.f);
    rstd = rsqrtf(st.y*(1.f/256.f) - mu*mu + 1e-5f);
  }

  f32x4 acc[4][4] = {};
  float4 pa[4], pb[4];
  u16x4 qa[4], qbh[4], qbl[4];

  auto LOADT = [&](int t){
    #pragma unroll
    for (int g = 0; g < 4; ++g){
      if constexpr (APRE==0) pa[g] = *(const float4*)&Apf[t*32 + g*4];
      else                   qa[g] = *(const u16x4*)&Apb[t*32 + g*4];
    }
    #pragma unroll
    for (int g = 0; g < 4; ++g){
      if constexpr (BPRE==0) pb[g] = *(const float4*)&Bpf[(size_t)t*32*N + g*4];
      else {
        qbh[g] = *(const u16x4*)&Bph[(size_t)t*32*N + g*4];
        qbl[g] = *(const u16x4*)&Bpl[(size_t)t*32*N + g*4];
      }
    }
  };
  auto STAGE = [&](int t){
    #pragma unroll
    for (int g = 0; g < 4; ++g){
      int idx = sar * LDR + ((sak + g * 4) ^ cA);
      if constexpr (APRE==0){
        float xs[4] = {pa[g].x, pa[g].y, pa[g].z, pa[g].w};
        if constexpr (LNA==1){
          float4 gv = *(const float4*)&lng[t*32 + sak + g*4];
          float4 bv = *(const float4*)&lnb[t*32 + sak + g*4];
          xs[0] = (xs[0]-mu)*rstd*gv.x + bv.x;
          xs[1] = (xs[1]-mu)*rstd*gv.y + bv.y;
          xs[2] = (xs[2]-mu)*rstd*gv.z + bv.z;
          xs[3] = (xs[3]-mu)*rstd*gv.w + bv.w;
        }
        u16x4 h, l;
        #pragma unroll
        for (int e = 0; e < 4; ++e){ unsigned short hh, ll; tsplit(xs[e], hh, ll); h[e]=hh; l[e]=ll; }
        *(u16x4*)&Ah[idx] = h; *(u16x4*)&Al[idx] = l;
      } else {
        *(u16x4*)&Ah[idx] = qa[g];
      }
    }
    int kx = sbk ^ cB;
    #pragma unroll
    for (int g = 0; g < 4; ++g){
      if constexpr (BPRE==0){
        float xs[4] = {pb[g].x, pb[g].y, pb[g].z, pb[g].w};
        #pragma unroll
        for (int e = 0; e < 4; ++e){
          int n = sbn + g * 4 + e;
          unsigned short hh, ll; tsplit(xs[e], hh, ll);
          Bh[n * LDR + kx] = hh; Bl[n * LDR + kx] = ll;
        }
      } else {
        #pragma unroll
        for (int e = 0; e < 4; ++e){
          int n = sbn + g * 4 + e;
          Bh[n * LDR + kx] = qbh[g][e]; Bl[n * LDR + kx] = qbl[g][e];
        }
      }
    }
  };

  LOADT(0);
  STAGE(0);
  __syncthreads();

  for (int t = 0; t < NT; ++t){
    if (t + 1 < NT) LOADT(t + 1);
    short8 bh[4], bl[4];
    #pragma unroll
    for (int ct = 0; ct < 4; ++ct){
      int n = wn0 + ct * 16 + rowb;
      int idx = n * LDR + (kb ^ (((n >> 4) & 3) << 3));
      bh[ct] = *(const short8*)&Bh[idx];
      bl[ct] = *(const short8*)&Bl[idx];
    }
    #pragma unroll
    for (int rt = 0; rt < 4; ++rt){
      int r = wm0 + rt * 16 + rowb;
      int idx = r * LDR + (kb ^ (((r >> 3) & 3) << 3));
      short8 ah = *(const short8*)&Ah[idx];
      #pragma unroll
      for (int ct = 0; ct < 4; ++ct){
        acc[rt][ct] = __builtin_amdgcn_mfma_f32_16x16x32_bf16(ah, bh[ct], acc[rt][ct], 0, 0, 0);
        acc[rt][ct] = __builtin_amdgcn_mfma_f32_16x16x32_bf16(ah, bl[ct], acc[rt][ct], 0, 0, 0);
      }
      if constexpr (APRE==0){
        short8 al = *(const short8*)&Al[idx];
        #pragma unroll
        for (int ct = 0; ct < 4; ++ct)
          acc[rt][ct] = __builtin_amdgcn_mfma_f32_16x16x32_bf16(al, bh[ct], acc[rt][ct], 0, 0, 0);
      }
    }
    if (t + 1 < NT){
      __syncthreads();
      STAGE(t + 1);
      __syncthreads();
    }
  }

  // epilogue: C/D layout col=lane&15, row=(lane>>4)*4+q  (HW-verified)
  float bvv[4];
  #pragma unroll
  for (int ct = 0; ct < 4; ++ct) bvv[ct] = bias[n0 + wn0 + ct*16 + rowb];
  #pragma unroll
  for (int rt = 0; rt < 4; ++rt){
    #pragma unroll
    for (int q = 0; q < 4; ++q){
      int gr = m0 + wm0 + rt*16 + (lane >> 4)*4 + q;
      float rs = 0.f, rq = 0.f;
      #pragma unroll
      for (int ct = 0; ct < 4; ++ct){
        int gc = n0 + wn0 + ct*16 + rowb;
        size_t off = (size_t)gr*N + gc;
        float v = acc[rt][ct][q] + bvv[ct];
        if constexpr (EPI == 1) v = fmaxf(v, 0.f);
        if constexpr (EPI == 2) v += resid[off];
        if constexpr (EPI == 3) outb[off] = f2bf(fmaxf(v, 0.f));
        else                    outf[off] = v;
        if constexpr (SOUT == 1){ rs += v; rq += v*v; }
      }
      if constexpr (SOUT == 1){
        rs += __shfl_xor(rs, 1); rq += __shfl_xor(rq, 1);
        rs += __shfl_xor(rs, 2); rq += __shfl_xor(rq, 2);
        rs += __shfl_xor(rs, 4); rq += __shfl_xor(rq, 4);
        rs += __shfl_xor(rs, 8); rq += __shfl_xor(rq, 8);
        if (rowb == 0){
          atomicAdd(&stout[gr].x, rs);
          atomicAdd(&stout[gr].y, rq);
        }
      }
    }
  }
}

// ---------------------------------------------------------------- attention v8 (MFMA flash)
// v6's amortized structure (1024 threads, qc=4 -> 4 stagings per (b,h); v7's
// qc=8 doubled staging and regressed) + v7's 2-term QK (no K-lo plane:
// -33% QK MFMAs, 73 KB LDS). Also zeroes st2 (next LN's accumulation target)
// from the qc==0,h==0 blocks. Frag layouts HW-verified rounds 7-11.
__global__ __launch_bounds__(1024) void attn_v8(
    const float* __restrict__ qkv, float* __restrict__ o, float2* __restrict__ stz)
{
  constexpr int LDK = 40;
  constexpr int LDV = 520;
  __shared__ unsigned short Khi[512*LDK];   // 40 KB
  __shared__ unsigned short Vt[32*LDV];     // 32.5 KB
  __shared__ float cbuf[16][16];

  const int tid = threadIdx.x;
  const int qc = blockIdx.x, h = blockIdx.y, b = blockIdx.z;
  const float* base = qkv + (size_t)b*1024*768;
  const int hoff = h*32;
  const float sc = 0.17677669529663687f;

  if (stz && qc == 0 && h == 0) stz[b*1024 + tid] = make_float2(0.f, 0.f);

  #pragma unroll
  for (int t = 0; t < 4; ++t){
    int i = tid + t*1024;
    int row = i >> 3, c4 = (i & 7) * 4;
    float4 kv = *(const float4*)&base[(size_t)row*768 + 256 + hoff + c4];
    float ks[4] = {kv.x, kv.y, kv.z, kv.w};
    u16x4 hk;
    #pragma unroll
    for (int e = 0; e < 4; ++e) hk[e] = f2bf(ks[e]);
    *(u16x4*)&Khi[row*LDK + c4] = hk;
    float4 vv = *(const float4*)&base[(size_t)row*768 + 512 + hoff + c4];
    float vs[4] = {vv.x, vv.y, vv.z, vv.w};
    #pragma unroll
    for (int e = 0; e < 4; ++e)
      Vt[(c4 + e)*LDV + row] = f2bf(vs[e]);
  }

  const int wv = tid >> 6, lane = tid & 63;
  const int g = lane >> 4, r = lane & 15;
  const int q0w = qc*256 + wv*16;

  short8 qh, ql;
  {
    const float* qp = &base[(size_t)(q0w + r)*768 + hoff + g*8];
    float4 a = *(const float4*)qp;
    float4 c = *(const float4*)(qp + 4);
    float xs[8] = {a.x*sc, a.y*sc, a.z*sc, a.w*sc, c.x*sc, c.y*sc, c.z*sc, c.w*sc};
    #pragma unroll
    for (int e = 0; e < 8; ++e){
      unsigned short hb_ = f2bf(xs[e]);
      qh[e] = (short)hb_;
      ql[e] = (short)f2bf(xs[e] - bf2f(hb_));
    }
  }
  __syncthreads();

  float m = -1e30f, l = 0.f;
  f32x4 O0 = {0.f,0.f,0.f,0.f}, O1 = {0.f,0.f,0.f,0.f};

  for (int st = 0; st < 16; ++st){
    int key0 = st*32 + (r >> 2)*8 + (r & 3);
    short8 ah0 = *(const short8*)&Khi[key0*LDK + g*8];
    short8 ah1 = *(const short8*)&Khi[(key0+4)*LDK + g*8];
    f32x4 s0 = {0.f,0.f,0.f,0.f}, s1 = {0.f,0.f,0.f,0.f};
    s0 = __builtin_amdgcn_mfma_f32_16x16x32_bf16(ah0, qh, s0, 0,0,0);
    s0 = __builtin_amdgcn_mfma_f32_16x16x32_bf16(ah0, ql, s0, 0,0,0);
    s1 = __builtin_amdgcn_mfma_f32_16x16x32_bf16(ah1, qh, s1, 0,0,0);
    s1 = __builtin_amdgcn_mfma_f32_16x16x32_bf16(ah1, ql, s1, 0,0,0);
    float pv[8] = {s0[0],s0[1],s0[2],s0[3], s1[0],s1[1],s1[2],s1[3]};
    float tm = pv[0];
    #pragma unroll
    for (int j = 1; j < 8; ++j) tm = fmaxf(tm, pv[j]);
    tm = fmaxf(tm, __shfl_xor(tm, 16));
    tm = fmaxf(tm, __shfl_xor(tm, 32));
    float mn = fmaxf(m, tm);
    float ts = 0.f;
    #pragma unroll
    for (int j = 0; j < 8; ++j){ pv[j] = __expf(pv[j] - mn); ts += pv[j]; }
    ts += __shfl_xor(ts, 16);
    ts += __shfl_xor(ts, 32);
    if (__any(mn > m)){
      float corr = __expf(m - mn);
      if (lane < 16) cbuf[wv][lane] = corr;
      asm volatile("s_waitcnt lgkmcnt(0)" ::: "memory");
      f32x4 cf = *(const f32x4*)&cbuf[wv][g*4];
      #pragma unroll
      for (int j = 0; j < 4; ++j){ O0[j] *= cf[j]; O1[j] *= cf[j]; }
      l *= corr;
      m = mn;
    }
    l += ts;
    short8 pa;
    #pragma unroll
    for (int j = 0; j < 8; ++j) pa[j] = (short)f2bf(pv[j]);
    short8 v0 = *(const short8*)&Vt[(size_t)r*LDV + st*32 + g*8];
    short8 v1 = *(const short8*)&Vt[(size_t)(r+16)*LDV + st*32 + g*8];
    O0 = __builtin_amdgcn_mfma_f32_16x16x32_bf16(pa, v0, O0, 0,0,0);
    O1 = __builtin_amdgcn_mfma_f32_16x16x32_bf16(pa, v1, O1, 0,0,0);
  }

  // ---- self-attend tile (targets only): diagonal-masked, K/V from global
  if (qc >= 2){
    const float* kp = &base[(size_t)(q0w + r)*768 + 256 + hoff + g*8];
    float4 a = *(const float4*)kp;
    float4 c = *(const float4*)(kp + 4);
    float xs[8] = {a.x, a.y, a.z, a.w, c.x, c.y, c.z, c.w};
    short8 kh8;
    #pragma unroll
    for (int e = 0; e < 8; ++e) kh8[e] = (short)f2bf(xs[e]);
    f32x4 s = {0.f,0.f,0.f,0.f};
    s = __builtin_amdgcn_mfma_f32_16x16x32_bf16(kh8, qh, s, 0,0,0);
    s = __builtin_amdgcn_mfma_f32_16x16x32_bf16(kh8, ql, s, 0,0,0);
    float pv[8] = {0.f,0.f,0.f,0.f,0.f,0.f,0.f,0.f};
    float tm = -1e30f;
    #pragma unroll
    for (int j = 0; j < 4; ++j){
      bool al_ = (g*4 + j) == r;
      tm = fmaxf(tm, al_ ? s[j] : -1e30f);
    }
    tm = fmaxf(tm, __shfl_xor(tm, 16));
    tm = fmaxf(tm, __shfl_xor(tm, 32));
    float mn = fmaxf(m, tm);
    float ts = 0.f;
    #pragma unroll
    for (int j = 0; j < 4; ++j){
      bool al_ = (g*4 + j) == r;
      pv[j] = al_ ? __expf(s[j] - mn) : 0.f;
      ts += pv[j];
    }
    ts += __shfl_xor(ts, 16);
    ts += __shfl_xor(ts, 32);
    if (__any(mn > m)){
      float corr = __expf(m - mn);
      if (lane < 16) cbuf[wv][lane] = corr;
      asm volatile("s_waitcnt lgkmcnt(0)" ::: "memory");
      f32x4 cf = *(const f32x4*)&cbuf[wv][g*4];
      #pragma unroll
      for (int j = 0; j < 4; ++j){ O0[j] *= cf[j]; O1[j] *= cf[j]; }
      l *= corr;
      m = mn;
    }
    l += ts;
    short8 pa, v0, v1;
    #pragma unroll
    for (int j = 0; j < 8; ++j) pa[j] = (short)f2bf(pv[j]);
    #pragma unroll
    for (int j = 0; j < 4; ++j){
      const float* vp = &base[(size_t)(q0w + g*4 + j)*768 + 512 + hoff];
      v0[j] = (short)f2bf(vp[r]);
      v1[j] = (short)f2bf(vp[r + 16]);
      v0[j+4] = 0; v1[j+4] = 0;
    }
    O0 = __builtin_amdgcn_mfma_f32_16x16x32_bf16(pa, v0, O0, 0,0,0);
    O1 = __builtin_amdgcn_mfma_f32_16x16x32_bf16(pa, v1, O1, 0,0,0);
  }

  float inv = 1.f / l;
  if (lane < 16) cbuf[wv][lane] = inv;
  asm volatile("s_waitcnt lgkmcnt(0)" ::: "memory");
  f32x4 iv = *(const f32x4*)&cbuf[wv][g*4];
  float* op = o + ((size_t)b*1024 + q0w + g*4)*256 + hoff;
  #pragma unroll
  for (int j = 0; j < 4; ++j){
    op[(size_t)j*256 + r]      = O0[j] * iv[j];
    op[(size_t)j*256 + r + 16] = O1[j] * iv[j];
  }
}

// ---------------------------------------------------------------- launch
extern "C" void kernel_launch(void* const* d_in, const int* in_sizes, int n_in,
                              void* d_out, int out_size, void* d_ws, size_t ws_size,
                              hipStream_t stream)
{
  (void)in_sizes; (void)n_in; (void)out_size;
  const float* xc   = (const float*)d_in[0];
  const float* yc   = (const float*)d_in[1];
  const float* xt   = (const float*)d_in[2];
  const float* eW1  = (const float*)d_in[3];
  const float* eb1  = (const float*)d_in[4];
  const float* eW2  = (const float*)d_in[5];
  const float* eb2  = (const float*)d_in[6];
  const float* Wqkv = (const float*)d_in[7];
  const float* bqkv = (const float*)d_in[8];
  const float* Wo   = (const float*)d_in[9];
  const float* bo   = (const float*)d_in[10];
  const float* ln1g = (const float*)d_in[11];
  const float* ln1b = (const float*)d_in[12];
  const float* ln2g = (const float*)d_in[13];
  const float* ln2b = (const float*)d_in[14];
  const float* Wff1 = (const float*)d_in[15];
  const float* bff1 = (const float*)d_in[16];
  const float* Wff2 = (const float*)d_in[17];
  const float* bff2 = (const float*)d_in[18];

  float* zf = (float*)d_out;            // residual stream [8][1024][256] f32 = 8 MB
  char* ws = (char*)d_ws;
  float* hb      = (float*)(ws);                        // 8 MiB (attn out / enc hid)
  float* scratch = (float*)(ws + (size_t)8*1024*1024);  // qkv f32 (24 MiB) / ffh bf16 (16 MiB)

  const size_t MiB = 1024*1024;
  const bool hugews = (ws_size == 0) || (ws_size >= 64*MiB);   // fill counters show ws = 256 MiB
  const bool bigws  = (ws_size == 0) || (ws_size >= 33*MiB);

  if (hugews){
    // persistent split planes at ws+32MiB (~18.3 MiB) + LN stat sums at ws+52MiB
    unsigned short* W = (unsigned short*)(ws + 32*MiB);
    unsigned short* qkvh_a = W;                 // 6*196608
    unsigned short* qkvl_a = W + 1179648;
    unsigned short* woh_a  = W + 2359296;       // 6*65536
    unsigned short* wol_a  = W + 2752512;
    unsigned short* w1h_a  = W + 3145728;       // 6*262144
    unsigned short* w1l_a  = W + 4718592;
    unsigned short* w2h_a  = W + 6291456;
    unsigned short* w2l_a  = W + 7864320;
    unsigned short* e2h    = W + 9437184;       // 65536
    unsigned short* e2l    = W + 9502720;
    float2* st1 = (float2*)(ws + 52*MiB);       // (sum, sumsq) per row, 64 KB
    float2* st2 = st1 + 8192;
    unsigned short* ffh_b  = (unsigned short*)scratch;   // 16 MiB, after attn

    conv2<<<1536, 256, 0, stream>>>((const float4*)Wqkv, 294912, (u16x4*)qkvh_a, (u16x4*)qkvl_a,
                                    (const float4*)Wo,    98304, (u16x4*)woh_a,  (u16x4*)wol_a);
    conv2<<<3072, 256, 0, stream>>>((const float4*)Wff1, 393216, (u16x4*)w1h_a, (u16x4*)w1l_a,
                                    (const float4*)Wff2, 393216, (u16x4*)w2h_a, (u16x4*)w2l_a);
    conv2<<<64, 256, 0, stream>>>((const float4*)eW2, 16384, (u16x4*)e2h, (u16x4*)e2l,
                                  nullptr, 0, nullptr, nullptr);

    // encoder: s1 zeroes st1; enc-gemm writes z AND accumulates st1 (layer-0 LN1)
    encoder_s1<<<8192, 256, 0, stream>>>(xc, yc, xt, eW1, eb1, hb, st1);
    gemm_mfma<0,1,0,0,1><<<dim3(2,64), 256, 0, stream>>>(hb, nullptr, nullptr, e2h, e2l,
                                                         nullptr, nullptr, nullptr, eb2, nullptr,
                                                         zf, nullptr, st1, nullptr, 256, 256);

    for (int l=0; l<6; l++){
      unsigned short* qkvh = qkvh_a + (size_t)l*196608;
      unsigned short* qkvl = qkvl_a + (size_t)l*196608;
      unsigned short* woh  = woh_a  + (size_t)l*65536;
      unsigned short* wol  = wol_a  + (size_t)l*65536;
      unsigned short* w1h  = w1h_a  + (size_t)l*262144;
      unsigned short* w1l  = w1l_a  + (size_t)l*262144;
      unsigned short* w2h  = w2h_a  + (size_t)l*262144;
      unsigned short* w2l  = w2l_a  + (size_t)l*262144;

      // qkv = LN1(z) @ Wq  (LN applied during A-staging from st1 sums)
      gemm_mfma<0,1,0,1,0><<<dim3(6,64), 256, 0, stream>>>(zf, nullptr, nullptr, qkvh, qkvl,
                                                           st1, ln1g+l*256, ln1b+l*256,
                                                           bqkv+l*768, nullptr, scratch, nullptr,
                                                           nullptr, nullptr, 768, 256);
      attn_v8<<<dim3(4,8,8), 1024, 0, stream>>>(scratch, hb, st2);    // zeroes st2
      // proj: z += attn@Wo, accumulating st2 (LN2 stats) in the epilogue
      gemm_mfma<0,1,2,0,1><<<dim3(2,64), 256, 0, stream>>>(hb, nullptr, nullptr, woh, wol,
                                                           nullptr, nullptr, nullptr, bo+l*256, zf,
                                                           zf, nullptr, st2, nullptr, 256, 256);
      // ff1 = relu(LN2(z) @ W1) -> bf16; zeroes st1 for ff2's accumulation
      gemm_mfma<0,1,3,1,0><<<dim3(8,64), 256, 0, stream>>>(zf, nullptr, nullptr, w1h, w1l,
                                                           st2, ln2g+l*256, ln2b+l*256,
                                                           bff1+l*1024, nullptr, nullptr, ffh_b,
                                                           nullptr, st1, 1024, 256);
      // ff2: z += ffh@W2, accumulating st1 (next layer's LN1 stats)
      gemm_mfma<1,1,2,0,1><<<dim3(2,64), 256, 0, stream>>>(nullptr, ffh_b, nullptr, w2h, w2l,
                                                           nullptr, nullptr, nullptr, bff2+l*256, zf,
                                                           zf, nullptr, st1, nullptr, 256, 1024);
    }
  } else if (bigws){
    // round-10 layout: per-layer conv + separate ln_v2 (no stats fusion)
    unsigned short* wsA = (unsigned short*)(ws + 32*MiB);
    unsigned short* wsB = (unsigned short*)(ws + 24*MiB);
    unsigned short* qkvh = wsA,            * qkvl = wsA + 196608;
    unsigned short* woh  = wsA + 393216,   * wol  = wsA + 458752;
    unsigned short* w1h  = wsB,            * w1l  = wsB + 262144;
    unsigned short* w2h  = wsB + 524288,   * w2l  = wsB + 786432;
    unsigned short* ffh_b = (unsigned short*)scratch;

    conv2<<<64, 256, 0, stream>>>((const float4*)eW2, 16384, (u16x4*)wsA, (u16x4*)(wsA+65536),
                                  nullptr, 0, nullptr, nullptr);
    encoder_s1<<<8192, 256, 0, stream>>>(xc, yc, xt, eW1, eb1, hb, nullptr);
    gemm_mfma<0,1,0,0,0><<<dim3(2,64), 256, 0, stream>>>(hb, nullptr, nullptr, wsA, wsA+65536,
                                                         nullptr, nullptr, nullptr, eb2, nullptr,
                                                         zf, nullptr, nullptr, nullptr, 256, 256);
    for (int l=0; l<6; l++){
      const float* Wq = Wqkv + (size_t)l*256*768;
      const float* Wl = Wo   + (size_t)l*256*256;
      const float* W1 = Wff1 + (size_t)l*256*1024;
      const float* W2 = Wff2 + (size_t)l*1024*256;

      conv2<<<256, 256, 0, stream>>>((const float4*)Wq, 49152, (u16x4*)qkvh, (u16x4*)qkvl,
                                     (const float4*)Wl, 16384, (u16x4*)woh,  (u16x4*)wol);
      ln_v2<<<2048, 256, 0, stream>>>(zf, ln1g+l*256, ln1b+l*256, hb);
      gemm_mfma<0,1,0,0,0><<<dim3(6,64), 256, 0, stream>>>(hb, nullptr, nullptr, qkvh, qkvl,
                                                           nullptr, nullptr, nullptr,
                                                           bqkv+l*768, nullptr, scratch, nullptr,
                                                           nullptr, nullptr, 768, 256);
      attn_v8<<<dim3(4,8,8), 1024, 0, stream>>>(scratch, hb, nullptr);
      conv2<<<512, 256, 0, stream>>>((const float4*)W1, 65536, (u16x4*)w1h, (u16x4*)w1l,
                                     (const float4*)W2, 65536, (u16x4*)w2h, (u16x4*)w2l);
      gemm_mfma<0,1,2,0,0><<<dim3(2,64), 256, 0, stream>>>(hb, nullptr, nullptr, woh, wol,
                                                           nullptr, nullptr, nullptr, bo+l*256, zf,
                                                           zf, nullptr, nullptr, nullptr, 256, 256);
      ln_v2<<<2048, 256, 0, stream>>>(zf, ln2g+l*256, ln2b+l*256, hb);
      gemm_mfma<0,1,3,0,0><<<dim3(8,64), 256, 0, stream>>>(hb, nullptr, nullptr, w1h, w1l,
                                                           nullptr, nullptr, nullptr,
                                                           bff1+l*1024, nullptr, nullptr, ffh_b,
                                                           nullptr, nullptr, 1024, 256);
      gemm_mfma<1,1,2,0,0><<<dim3(2,64), 256, 0, stream>>>(nullptr, ffh_b, nullptr, w2h, w2l,
                                                           nullptr, nullptr, nullptr, bff2+l*256, zf,
                                                           zf, nullptr, nullptr, nullptr, 256, 1024);
    }
  } else {
    // minimal-ws fallback: in-kernel conversion + separate LN, chunked scratch
    encoder_s1<<<8192, 256, 0, stream>>>(xc, yc, xt, eW1, eb1, hb, nullptr);
    gemm_mfma<0,0,0,0,0><<<dim3(2,64), 256, 0, stream>>>(hb, nullptr, eW2, nullptr, nullptr,
                                                         nullptr, nullptr, nullptr, eb2, nullptr,
                                                         zf, nullptr, nullptr, nullptr, 256, 256);
    for (int l=0; l<6; l++){
      const float* Wq = Wqkv + (size_t)l*256*768;
      const float* Wl = Wo   + (size_t)l*256*256;
      const float* W1 = Wff1 + (size_t)l*256*1024;
      const float* W2 = Wff2 + (size_t)l*1024*256;

      ln_v2<<<2048, 256, 0, stream>>>(zf, ln1g+l*256, ln1b+l*256, hb);
      for (int c=0; c<4; c++){
        float* hrows = hb + (size_t)c*2048*256;
        gemm_mfma<0,0,0,0,0><<<dim3(6,16), 256, 0, stream>>>(hrows, nullptr, Wq, nullptr, nullptr,
                                                             nullptr, nullptr, nullptr,
                                                             bqkv+l*768, nullptr, scratch, nullptr,
                                                             nullptr, nullptr, 768, 256);
        attn_v8<<<dim3(4,8,2), 1024, 0, stream>>>(scratch, hrows, nullptr);
      }
      gemm_mfma<0,0,2,0,0><<<dim3(2,64), 256, 0, stream>>>(hb, nullptr, Wl, nullptr, nullptr,
                                                           nullptr, nullptr, nullptr, bo+l*256, zf,
                                                           zf, nullptr, nullptr, nullptr, 256, 256);
      ln_v2<<<2048, 256, 0, stream>>>(zf, ln2g+l*256, ln2b+l*256, hb);
      for (int c=0; c<4; c++){
        float* hrows = hb + (size_t)c*2048*256;
        float* zrows = zf + (size_t)c*2048*256;
        gemm_mfma<0,0,1,0,0><<<dim3(8,16), 256, 0, stream>>>(hrows, nullptr, W1, nullptr, nullptr,
                                                             nullptr, nullptr, nullptr,
                                                             bff1+l*1024, nullptr, scratch, nullptr,
                                                             nullptr, nullptr, 1024, 256);
        gemm_mfma<0,0,2,0,0><<<dim3(2,16), 256, 0, stream>>>(scratch, nullptr, W2, nullptr, nullptr,
                                                             nullptr, nullptr, nullptr,
                                                             bff2+l*256, zrows, zrows, nullptr,
                                                             nullptr, nullptr, 256, 1024);
      }
    }
  }
}

// Round 14
// 820.648 us; speedup vs baseline: 1.0824x; 1.0824x over previous
//
#include <hip/hip_runtime.h>

typedef short short8 __attribute__((ext_vector_type(8)));
typedef float f32x4 __attribute__((ext_vector_type(4)));
typedef unsigned short u16x4 __attribute__((ext_vector_type(4)));

// f32 -> bf16 bits (round-to-nearest-even; finite inputs only)
__device__ __forceinline__ unsigned short f2bf(float x){
  unsigned int u = __float_as_uint(x);
  u = u + 0x7FFFu + ((u >> 16) & 1u);
  return (unsigned short)(u >> 16);
}
__device__ __forceinline__ float bf2f(unsigned short h){
  return __uint_as_float(((unsigned int)h) << 16);
}
// truncation split: hi = trunc16(x), lo = RNE(x - hi). |err| <= 2^-17 |x|.
__device__ __forceinline__ void tsplit(float x, unsigned short& h, unsigned short& l){
  unsigned int u = __float_as_uint(x);
  h = (unsigned short)(u >> 16);
  l = f2bf(x - __uint_as_float(u & 0xFFFF0000u));
}

// ---------------------------------------------------------------- weight split conv
// Bulk: layer-stacked weights are contiguous -> 3 dispatches convert all layers.
__global__ __launch_bounds__(256) void conv2(
    const float4* __restrict__ S0, int n0, u16x4* __restrict__ D0h, u16x4* __restrict__ D0l,
    const float4* __restrict__ S1, int n1, u16x4* __restrict__ D1h, u16x4* __restrict__ D1l)
{
  int i = blockIdx.x*256 + threadIdx.x;
  const float4* S; u16x4 *Dh, *Dl;
  if (i < n0){ S = S0 + i; Dh = D0h + i; Dl = D0l + i; }
  else { i -= n0; if (i >= n1) return; S = S1 + i; Dh = D1h + i; Dl = D1l + i; }
  float4 v = *S;
  float xs[4] = {v.x, v.y, v.z, v.w};
  u16x4 h, l;
  #pragma unroll
  for (int e = 0; e < 4; ++e){ unsigned short hh, ll; tsplit(xs[e], hh, ll); h[e]=hh; l[e]=ll; }
  *Dh = h; *Dl = l;
}

// ---------------------------------------------------------------- encoder stage 1
__global__ __launch_bounds__(256) void encoder_s1(
    const float* __restrict__ xc, const float* __restrict__ yc, const float* __restrict__ xt,
    const float* __restrict__ W1, const float* __restrict__ b1,
    float* __restrict__ hid)
{
  __shared__ float zin[10];
  int blk = blockIdx.x; int b = blk>>10; int t = blk & 1023;
  int tid = threadIdx.x;
  if (tid < 10){
    float v;
    if (tid < 8)      v = (t<512) ? xc[((size_t)b*512+t)*8+tid] : xt[((size_t)b*512+(t-512))*8+tid];
    else if (tid==8)  v = (t<512) ? yc[(size_t)b*512+t] : 0.f;
    else              v = (t<512) ? 0.f : 1.f;
    zin[tid]=v;
  }
  __syncthreads();
  float s = b1[tid];
  #pragma unroll
  for (int i=0;i<10;i++) s += zin[i]*W1[i*256+tid];
  hid[(size_t)blk*256 + tid] = fmaxf(s, 0.f);
}

// ---------------------------------------------------------------- layernorm v2
// Standalone LN (round-13 lesson: LN fused into GEMM A-staging sits on the
// double-buffer critical path x NT stagings and LOST vs this streaming kernel;
// rounds 11-13 all regressed vs this structure. Keep LN separate.)
__global__ __launch_bounds__(256) void ln_v2(const float* __restrict__ z,
    const float* __restrict__ g, const float* __restrict__ be, float* __restrict__ h)
{
  const int row = blockIdx.x*4 + (threadIdx.x>>6);
  const int lane = threadIdx.x & 63;
  float4 x = *(const float4*)&z[(size_t)row*256 + lane*4];
  float s = (x.x+x.y)+(x.z+x.w);
  #pragma unroll
  for (int off=32; off; off>>=1) s += __shfl_xor(s, off);
  float mu = s * (1.f/256.f);
  float dx = x.x-mu, dy = x.y-mu, dz = x.z-mu, dw = x.w-mu;
  float v = (dx*dx+dy*dy)+(dz*dz+dw*dw);
  #pragma unroll
  for (int off=32; off; off>>=1) v += __shfl_xor(v, off);
  float r = rsqrtf(v*(1.f/256.f) + 1e-5f);
  float4 gv = *(const float4*)&g[lane*4];
  float4 bv = *(const float4*)&be[lane*4];
  float4 o;
  o.x = dx*r*gv.x + bv.x; o.y = dy*r*gv.y + bv.y;
  o.z = dz*r*gv.z + bv.z; o.w = dw*r*gv.w + bv.w;
  *(float4*)&h[(size_t)row*256 + lane*4] = o;
}

// ---------------------------------------------------------------- gemm_mfma
// out = EPI(A @ B + bias). 128x128 block, 4 waves, split-bf16 MFMA.
// APRE: 0 = A f32 (trunc-split in kernel)  1 = A bf16 plane (2-term MFMA)
// BPRE: 0 = B f32 (split in kernel)        1 = B pre-split hi/lo planes (copy)
// EPI : 0 plain f32 ; 1 relu f32 ; 2 +resid f32 ; 3 relu -> bf16 out
// Round-10 configuration (measured best, 846us). No LN fusion, no stats
// epilogue (rounds 11-13: both regressed -- staging-path work x NT loses to a
// separate streaming kernel). Frag layouts HW-verified rounds 7-13.
// No launch_bounds min-waves (R4/R5: it caps VGPRs at 256/W and spills).
template<int APRE, int BPRE, int EPI>
__global__ __launch_bounds__(256) void gemm_mfma(
    const float* __restrict__ Af, const unsigned short* __restrict__ Ab,
    const float* __restrict__ Bf,
    const unsigned short* __restrict__ Bhg, const unsigned short* __restrict__ Blg,
    const float* __restrict__ bias, const float* __restrict__ resid,
    float* __restrict__ outf, unsigned short* __restrict__ outb,
    int N, int K)
{
  constexpr int LDR = 40;
  __shared__ unsigned short Ah[128*LDR];
  __shared__ unsigned short Al[(APRE==0)?(128*LDR):8];
  __shared__ unsigned short Bh[128*LDR], Bl[128*LDR];

  const int tid = threadIdx.x;
  const int lane = tid & 63, wv = tid >> 6;
  const int wm0 = (wv >> 1) * 64, wn0 = (wv & 1) * 64;
  const int m0 = blockIdx.y * 128, n0 = blockIdx.x * 128;

  const int sar = tid >> 1, sak = (tid & 1) * 16;
  const int sbk = tid >> 3, sbn = (tid & 7) * 16;
  const int cA = ((sar >> 3) & 3) << 3;
  const int cB = ((sbn >> 4) & 3) << 3;

  const float* Apf = nullptr; const unsigned short* Apb = nullptr;
  if constexpr (APRE==0) Apf = Af + (size_t)(m0 + sar) * K + sak;
  else                   Apb = Ab + (size_t)(m0 + sar) * K + sak;
  const float* Bpf = nullptr; const unsigned short *Bph = nullptr, *Bpl = nullptr;
  if constexpr (BPRE==0) Bpf = Bf + (size_t)sbk * N + n0 + sbn;
  else { Bph = Bhg + (size_t)sbk * N + n0 + sbn; Bpl = Blg + (size_t)sbk * N + n0 + sbn; }

  const int rowb = lane & 15, kb = (lane >> 4) * 8;
  const int NT = K / 32;

  f32x4 acc[4][4] = {};
  float4 pa[4], pb[4];
  u16x4 qa[4], qbh[4], qbl[4];

  auto LOADT = [&](int t){
    #pragma unroll
    for (int g = 0; g < 4; ++g){
      if constexpr (APRE==0) pa[g] = *(const float4*)&Apf[t*32 + g*4];
      else                   qa[g] = *(const u16x4*)&Apb[t*32 + g*4];
    }
    #pragma unroll
    for (int g = 0; g < 4; ++g){
      if constexpr (BPRE==0) pb[g] = *(const float4*)&Bpf[(size_t)t*32*N + g*4];
      else {
        qbh[g] = *(const u16x4*)&Bph[(size_t)t*32*N + g*4];
        qbl[g] = *(const u16x4*)&Bpl[(size_t)t*32*N + g*4];
      }
    }
  };
  auto STAGE = [&](){
    #pragma unroll
    for (int g = 0; g < 4; ++g){
      int idx = sar * LDR + ((sak + g * 4) ^ cA);
      if constexpr (APRE==0){
        float xs[4] = {pa[g].x, pa[g].y, pa[g].z, pa[g].w};
        u16x4 h, l;
        #pragma unroll
        for (int e = 0; e < 4; ++e){ unsigned short hh, ll; tsplit(xs[e], hh, ll); h[e]=hh; l[e]=ll; }
        *(u16x4*)&Ah[idx] = h; *(u16x4*)&Al[idx] = l;
      } else {
        *(u16x4*)&Ah[idx] = qa[g];
      }
    }
    int kx = sbk ^ cB;
    #pragma unroll
    for (int g = 0; g < 4; ++g){
      if constexpr (BPRE==0){
        float xs[4] = {pb[g].x, pb[g].y, pb[g].z, pb[g].w};
        #pragma unroll
        for (int e = 0; e < 4; ++e){
          int n = sbn + g * 4 + e;
          unsigned short hh, ll; tsplit(xs[e], hh, ll);
          Bh[n * LDR + kx] = hh; Bl[n * LDR + kx] = ll;
        }
      } else {
        #pragma unroll
        for (int e = 0; e < 4; ++e){
          int n = sbn + g * 4 + e;
          Bh[n * LDR + kx] = qbh[g][e]; Bl[n * LDR + kx] = qbl[g][e];
        }
      }
    }
  };

  LOADT(0);
  STAGE();
  __syncthreads();

  for (int t = 0; t < NT; ++t){
    if (t + 1 < NT) LOADT(t + 1);
    short8 bh[4], bl[4];
    #pragma unroll
    for (int ct = 0; ct < 4; ++ct){
      int n = wn0 + ct * 16 + rowb;
      int idx = n * LDR + (kb ^ (((n >> 4) & 3) << 3));
      bh[ct] = *(const short8*)&Bh[idx];
      bl[ct] = *(const short8*)&Bl[idx];
    }
    #pragma unroll
    for (int rt = 0; rt < 4; ++rt){
      int r = wm0 + rt * 16 + rowb;
      int idx = r * LDR + (kb ^ (((r >> 3) & 3) << 3));
      short8 ah = *(const short8*)&Ah[idx];
      #pragma unroll
      for (int ct = 0; ct < 4; ++ct){
        acc[rt][ct] = __builtin_amdgcn_mfma_f32_16x16x32_bf16(ah, bh[ct], acc[rt][ct], 0, 0, 0);
        acc[rt][ct] = __builtin_amdgcn_mfma_f32_16x16x32_bf16(ah, bl[ct], acc[rt][ct], 0, 0, 0);
      }
      if constexpr (APRE==0){
        short8 al = *(const short8*)&Al[idx];
        #pragma unroll
        for (int ct = 0; ct < 4; ++ct)
          acc[rt][ct] = __builtin_amdgcn_mfma_f32_16x16x32_bf16(al, bh[ct], acc[rt][ct], 0, 0, 0);
      }
    }
    if (t + 1 < NT){
      __syncthreads();
      STAGE();
      __syncthreads();
    }
  }

  // epilogue: C/D layout col=lane&15, row=(lane>>4)*4+q  (HW-verified)
  #pragma unroll
  for (int ct = 0; ct < 4; ++ct){
    int gc = n0 + wn0 + ct * 16 + rowb;
    float bv = bias[gc];
    #pragma unroll
    for (int rt = 0; rt < 4; ++rt){
      int gr0 = m0 + wm0 + rt * 16 + (lane >> 4) * 4;
      #pragma unroll
      for (int q = 0; q < 4; ++q){
        size_t off = (size_t)(gr0 + q) * N + gc;
        float v = acc[rt][ct][q] + bv;
        if constexpr (EPI == 1) v = fmaxf(v, 0.f);
        if constexpr (EPI == 2) v += resid[off];
        if constexpr (EPI == 3) outb[off] = f2bf(fmaxf(v, 0.f));
        else                    outf[off] = v;
      }
    }
  }
}

// ---------------------------------------------------------------- attention v8 (MFMA flash)
// v6's amortized structure (1024 threads, qc=4 -> 4 stagings per (b,h); v7's
// qc=8 doubled staging and regressed) + 2-term QK (no K-lo plane: -33% QK
// MFMAs, 73 KB LDS). Frag layouts HW-verified rounds 7-13.
__global__ __launch_bounds__(1024) void attn_v8(
    const float* __restrict__ qkv, float* __restrict__ o)
{
  constexpr int LDK = 40;
  constexpr int LDV = 520;
  __shared__ unsigned short Khi[512*LDK];   // 40 KB
  __shared__ unsigned short Vt[32*LDV];     // 32.5 KB
  __shared__ float cbuf[16][16];

  const int tid = threadIdx.x;
  const int qc = blockIdx.x, h = blockIdx.y, b = blockIdx.z;
  const float* base = qkv + (size_t)b*1024*768;
  const int hoff = h*32;
  const float sc = 0.17677669529663687f;

  #pragma unroll
  for (int t = 0; t < 4; ++t){
    int i = tid + t*1024;
    int row = i >> 3, c4 = (i & 7) * 4;
    float4 kv = *(const float4*)&base[(size_t)row*768 + 256 + hoff + c4];
    float ks[4] = {kv.x, kv.y, kv.z, kv.w};
    u16x4 hk;
    #pragma unroll
    for (int e = 0; e < 4; ++e) hk[e] = f2bf(ks[e]);
    *(u16x4*)&Khi[row*LDK + c4] = hk;
    float4 vv = *(const float4*)&base[(size_t)row*768 + 512 + hoff + c4];
    float vs[4] = {vv.x, vv.y, vv.z, vv.w};
    #pragma unroll
    for (int e = 0; e < 4; ++e)
      Vt[(c4 + e)*LDV + row] = f2bf(vs[e]);
  }

  const int wv = tid >> 6, lane = tid & 63;
  const int g = lane >> 4, r = lane & 15;
  const int q0w = qc*256 + wv*16;

  short8 qh, ql;
  {
    const float* qp = &base[(size_t)(q0w + r)*768 + hoff + g*8];
    float4 a = *(const float4*)qp;
    float4 c = *(const float4*)(qp + 4);
    float xs[8] = {a.x*sc, a.y*sc, a.z*sc, a.w*sc, c.x*sc, c.y*sc, c.z*sc, c.w*sc};
    #pragma unroll
    for (int e = 0; e < 8; ++e){
      unsigned short hb_ = f2bf(xs[e]);
      qh[e] = (short)hb_;
      ql[e] = (short)f2bf(xs[e] - bf2f(hb_));
    }
  }
  __syncthreads();

  float m = -1e30f, l = 0.f;
  f32x4 O0 = {0.f,0.f,0.f,0.f}, O1 = {0.f,0.f,0.f,0.f};

  for (int st = 0; st < 16; ++st){
    int key0 = st*32 + (r >> 2)*8 + (r & 3);
    short8 ah0 = *(const short8*)&Khi[key0*LDK + g*8];
    short8 ah1 = *(const short8*)&Khi[(key0+4)*LDK + g*8];
    f32x4 s0 = {0.f,0.f,0.f,0.f}, s1 = {0.f,0.f,0.f,0.f};
    s0 = __builtin_amdgcn_mfma_f32_16x16x32_bf16(ah0, qh, s0, 0,0,0);
    s0 = __builtin_amdgcn_mfma_f32_16x16x32_bf16(ah0, ql, s0, 0,0,0);
    s1 = __builtin_amdgcn_mfma_f32_16x16x32_bf16(ah1, qh, s1, 0,0,0);
    s1 = __builtin_amdgcn_mfma_f32_16x16x32_bf16(ah1, ql, s1, 0,0,0);
    float pv[8] = {s0[0],s0[1],s0[2],s0[3], s1[0],s1[1],s1[2],s1[3]};
    float tm = pv[0];
    #pragma unroll
    for (int j = 1; j < 8; ++j) tm = fmaxf(tm, pv[j]);
    tm = fmaxf(tm, __shfl_xor(tm, 16));
    tm = fmaxf(tm, __shfl_xor(tm, 32));
    float mn = fmaxf(m, tm);
    float ts = 0.f;
    #pragma unroll
    for (int j = 0; j < 8; ++j){ pv[j] = __expf(pv[j] - mn); ts += pv[j]; }
    ts += __shfl_xor(ts, 16);
    ts += __shfl_xor(ts, 32);
    if (__any(mn > m)){
      float corr = __expf(m - mn);
      if (lane < 16) cbuf[wv][lane] = corr;
      asm volatile("s_waitcnt lgkmcnt(0)" ::: "memory");
      f32x4 cf = *(const f32x4*)&cbuf[wv][g*4];
      #pragma unroll
      for (int j = 0; j < 4; ++j){ O0[j] *= cf[j]; O1[j] *= cf[j]; }
      l *= corr;
      m = mn;
    }
    l += ts;
    short8 pa;
    #pragma unroll
    for (int j = 0; j < 8; ++j) pa[j] = (short)f2bf(pv[j]);
    short8 v0 = *(const short8*)&Vt[(size_t)r*LDV + st*32 + g*8];
    short8 v1 = *(const short8*)&Vt[(size_t)(r+16)*LDV + st*32 + g*8];
    O0 = __builtin_amdgcn_mfma_f32_16x16x32_bf16(pa, v0, O0, 0,0,0);
    O1 = __builtin_amdgcn_mfma_f32_16x16x32_bf16(pa, v1, O1, 0,0,0);
  }

  // ---- self-attend tile (targets only): diagonal-masked, K/V from global
  if (qc >= 2){
    const float* kp = &base[(size_t)(q0w + r)*768 + 256 + hoff + g*8];
    float4 a = *(const float4*)kp;
    float4 c = *(const float4*)(kp + 4);
    float xs[8] = {a.x, a.y, a.z, a.w, c.x, c.y, c.z, c.w};
    short8 kh8;
    #pragma unroll
    for (int e = 0; e < 8; ++e) kh8[e] = (short)f2bf(xs[e]);
    f32x4 s = {0.f,0.f,0.f,0.f};
    s = __builtin_amdgcn_mfma_f32_16x16x32_bf16(kh8, qh, s, 0,0,0);
    s = __builtin_amdgcn_mfma_f32_16x16x32_bf16(kh8, ql, s, 0,0,0);
    float pv[8] = {0.f,0.f,0.f,0.f,0.f,0.f,0.f,0.f};
    float tm = -1e30f;
    #pragma unroll
    for (int j = 0; j < 4; ++j){
      bool al_ = (g*4 + j) == r;
      tm = fmaxf(tm, al_ ? s[j] : -1e30f);
    }
    tm = fmaxf(tm, __shfl_xor(tm, 16));
    tm = fmaxf(tm, __shfl_xor(tm, 32));
    float mn = fmaxf(m, tm);
    float ts = 0.f;
    #pragma unroll
    for (int j = 0; j < 4; ++j){
      bool al_ = (g*4 + j) == r;
      pv[j] = al_ ? __expf(s[j] - mn) : 0.f;
      ts += pv[j];
    }
    ts += __shfl_xor(ts, 16);
    ts += __shfl_xor(ts, 32);
    if (__any(mn > m)){
      float corr = __expf(m - mn);
      if (lane < 16) cbuf[wv][lane] = corr;
      asm volatile("s_waitcnt lgkmcnt(0)" ::: "memory");
      f32x4 cf = *(const f32x4*)&cbuf[wv][g*4];
      #pragma unroll
      for (int j = 0; j < 4; ++j){ O0[j] *= cf[j]; O1[j] *= cf[j]; }
      l *= corr;
      m = mn;
    }
    l += ts;
    short8 pa, v0, v1;
    #pragma unroll
    for (int j = 0; j < 8; ++j) pa[j] = (short)f2bf(pv[j]);
    #pragma unroll
    for (int j = 0; j < 4; ++j){
      const float* vp = &base[(size_t)(q0w + g*4 + j)*768 + 512 + hoff];
      v0[j] = (short)f2bf(vp[r]);
      v1[j] = (short)f2bf(vp[r + 16]);
      v0[j+4] = 0; v1[j+4] = 0;
    }
    O0 = __builtin_amdgcn_mfma_f32_16x16x32_bf16(pa, v0, O0, 0,0,0);
    O1 = __builtin_amdgcn_mfma_f32_16x16x32_bf16(pa, v1, O1, 0,0,0);
  }

  float inv = 1.f / l;
  if (lane < 16) cbuf[wv][lane] = inv;
  asm volatile("s_waitcnt lgkmcnt(0)" ::: "memory");
  f32x4 iv = *(const f32x4*)&cbuf[wv][g*4];
  float* op = o + ((size_t)b*1024 + q0w + g*4)*256 + hoff;
  #pragma unroll
  for (int j = 0; j < 4; ++j){
    op[(size_t)j*256 + r]      = O0[j] * iv[j];
    op[(size_t)j*256 + r + 16] = O1[j] * iv[j];
  }
}

// ---------------------------------------------------------------- launch
extern "C" void kernel_launch(void* const* d_in, const int* in_sizes, int n_in,
                              void* d_out, int out_size, void* d_ws, size_t ws_size,
                              hipStream_t stream)
{
  (void)in_sizes; (void)n_in; (void)out_size;
  const float* xc   = (const float*)d_in[0];
  const float* yc   = (const float*)d_in[1];
  const float* xt   = (const float*)d_in[2];
  const float* eW1  = (const float*)d_in[3];
  const float* eb1  = (const float*)d_in[4];
  const float* eW2  = (const float*)d_in[5];
  const float* eb2  = (const float*)d_in[6];
  const float* Wqkv = (const float*)d_in[7];
  const float* bqkv = (const float*)d_in[8];
  const float* Wo   = (const float*)d_in[9];
  const float* bo   = (const float*)d_in[10];
  const float* ln1g = (const float*)d_in[11];
  const float* ln1b = (const float*)d_in[12];
  const float* ln2g = (const float*)d_in[13];
  const float* ln2b = (const float*)d_in[14];
  const float* Wff1 = (const float*)d_in[15];
  const float* bff1 = (const float*)d_in[16];
  const float* Wff2 = (const float*)d_in[17];
  const float* bff2 = (const float*)d_in[18];

  float* zf = (float*)d_out;            // residual stream [8][1024][256] f32 = 8 MB
  char* ws = (char*)d_ws;
  float* hb      = (float*)(ws);                        // 8 MiB (LN out / attn out / enc hid)
  float* scratch = (float*)(ws + (size_t)8*1024*1024);  // qkv f32 (24 MiB) / ffh bf16 (16 MiB)

  const size_t MiB = 1024*1024;
  const bool hugews = (ws_size == 0) || (ws_size >= 64*MiB);
  const bool bigws  = (ws_size == 0) || (ws_size >= 33*MiB);

  if (hugews){
    // persistent split planes at ws+32MiB (~18.3 MiB): bulk-converted once
    unsigned short* W = (unsigned short*)(ws + 32*MiB);
    unsigned short* qkvh_a = W;                 // 6*196608
    unsigned short* qkvl_a = W + 1179648;
    unsigned short* woh_a  = W + 2359296;       // 6*65536
    unsigned short* wol_a  = W + 2752512;
    unsigned short* w1h_a  = W + 3145728;       // 6*262144
    unsigned short* w1l_a  = W + 4718592;
    unsigned short* w2h_a  = W + 6291456;
    unsigned short* w2l_a  = W + 7864320;
    unsigned short* e2h    = W + 9437184;       // 65536
    unsigned short* e2l    = W + 9502720;
    unsigned short* ffh_b  = (unsigned short*)scratch;   // 16 MiB, after attn

    conv2<<<1536, 256, 0, stream>>>((const float4*)Wqkv, 294912, (u16x4*)qkvh_a, (u16x4*)qkvl_a,
                                    (const float4*)Wo,    98304, (u16x4*)woh_a,  (u16x4*)wol_a);
    conv2<<<3072, 256, 0, stream>>>((const float4*)Wff1, 393216, (u16x4*)w1h_a, (u16x4*)w1l_a,
                                    (const float4*)Wff2, 393216, (u16x4*)w2h_a, (u16x4*)w2l_a);
    conv2<<<64, 256, 0, stream>>>((const float4*)eW2, 16384, (u16x4*)e2h, (u16x4*)e2l,
                                  nullptr, 0, nullptr, nullptr);

    encoder_s1<<<8192, 256, 0, stream>>>(xc, yc, xt, eW1, eb1, hb);
    gemm_mfma<0,1,0><<<dim3(2,64), 256, 0, stream>>>(hb, nullptr, nullptr, e2h, e2l,
                                                     eb2, nullptr, zf, nullptr, 256, 256);

    for (int l=0; l<6; l++){
      unsigned short* qkvh = qkvh_a + (size_t)l*196608;
      unsigned short* qkvl = qkvl_a + (size_t)l*196608;
      unsigned short* woh  = woh_a  + (size_t)l*65536;
      unsigned short* wol  = wol_a  + (size_t)l*65536;
      unsigned short* w1h  = w1h_a  + (size_t)l*262144;
      unsigned short* w1l  = w1l_a  + (size_t)l*262144;
      unsigned short* w2h  = w2h_a  + (size_t)l*262144;
      unsigned short* w2l  = w2l_a  + (size_t)l*262144;

      ln_v2<<<2048, 256, 0, stream>>>(zf, ln1g+l*256, ln1b+l*256, hb);
      gemm_mfma<0,1,0><<<dim3(6,64), 256, 0, stream>>>(hb, nullptr, nullptr, qkvh, qkvl,
                                                       bqkv+l*768, nullptr, scratch, nullptr, 768, 256);
      attn_v8<<<dim3(4,8,8), 1024, 0, stream>>>(scratch, hb);
      gemm_mfma<0,1,2><<<dim3(2,64), 256, 0, stream>>>(hb, nullptr, nullptr, woh, wol,
                                                       bo+l*256, zf, zf, nullptr, 256, 256);
      ln_v2<<<2048, 256, 0, stream>>>(zf, ln2g+l*256, ln2b+l*256, hb);
      gemm_mfma<0,1,3><<<dim3(8,64), 256, 0, stream>>>(hb, nullptr, nullptr, w1h, w1l,
                                                       bff1+l*1024, nullptr, nullptr, ffh_b, 1024, 256);
      gemm_mfma<1,1,2><<<dim3(2,64), 256, 0, stream>>>(nullptr, ffh_b, nullptr, w2h, w2l,
                                                       bff2+l*256, zf, zf, nullptr, 256, 1024);
    }
  } else if (bigws){
    // per-layer conv (round-10 bigws layout)
    unsigned short* wsA = (unsigned short*)(ws + 32*MiB);
    unsigned short* wsB = (unsigned short*)(ws + 24*MiB);
    unsigned short* qkvh = wsA,            * qkvl = wsA + 196608;
    unsigned short* woh  = wsA + 393216,   * wol  = wsA + 458752;
    unsigned short* w1h  = wsB,            * w1l  = wsB + 262144;
    unsigned short* w2h  = wsB + 524288,   * w2l  = wsB + 786432;
    unsigned short* ffh_b = (unsigned short*)scratch;

    conv2<<<64, 256, 0, stream>>>((const float4*)eW2, 16384, (u16x4*)wsA, (u16x4*)(wsA+65536),
                                  nullptr, 0, nullptr, nullptr);
    encoder_s1<<<8192, 256, 0, stream>>>(xc, yc, xt, eW1, eb1, hb);
    gemm_mfma<0,1,0><<<dim3(2,64), 256, 0, stream>>>(hb, nullptr, nullptr, wsA, wsA+65536,
                                                     eb2, nullptr, zf, nullptr, 256, 256);
    for (int l=0; l<6; l++){
      const float* Wq = Wqkv + (size_t)l*256*768;
      const float* Wl = Wo   + (size_t)l*256*256;
      const float* W1 = Wff1 + (size_t)l*256*1024;
      const float* W2 = Wff2 + (size_t)l*1024*256;

      conv2<<<256, 256, 0, stream>>>((const float4*)Wq, 49152, (u16x4*)qkvh, (u16x4*)qkvl,
                                     (const float4*)Wl, 16384, (u16x4*)woh,  (u16x4*)wol);
      ln_v2<<<2048, 256, 0, stream>>>(zf, ln1g+l*256, ln1b+l*256, hb);
      gemm_mfma<0,1,0><<<dim3(6,64), 256, 0, stream>>>(hb, nullptr, nullptr, qkvh, qkvl,
                                                       bqkv+l*768, nullptr, scratch, nullptr, 768, 256);
      attn_v8<<<dim3(4,8,8), 1024, 0, stream>>>(scratch, hb);
      conv2<<<512, 256, 0, stream>>>((const float4*)W1, 65536, (u16x4*)w1h, (u16x4*)w1l,
                                     (const float4*)W2, 65536, (u16x4*)w2h, (u16x4*)w2l);
      gemm_mfma<0,1,2><<<dim3(2,64), 256, 0, stream>>>(hb, nullptr, nullptr, woh, wol,
                                                       bo+l*256, zf, zf, nullptr, 256, 256);
      ln_v2<<<2048, 256, 0, stream>>>(zf, ln2g+l*256, ln2b+l*256, hb);
      gemm_mfma<0,1,3><<<dim3(8,64), 256, 0, stream>>>(hb, nullptr, nullptr, w1h, w1l,
                                                       bff1+l*1024, nullptr, nullptr, ffh_b, 1024, 256);
      gemm_mfma<1,1,2><<<dim3(2,64), 256, 0, stream>>>(nullptr, ffh_b, nullptr, w2h, w2l,
                                                       bff2+l*256, zf, zf, nullptr, 256, 1024);
    }
  } else {
    // minimal-ws fallback: in-kernel conversion + separate LN, chunked scratch
    encoder_s1<<<8192, 256, 0, stream>>>(xc, yc, xt, eW1, eb1, hb);
    gemm_mfma<0,0,0><<<dim3(2,64), 256, 0, stream>>>(hb, nullptr, eW2, nullptr, nullptr,
                                                     eb2, nullptr, zf, nullptr, 256, 256);
    for (int l=0; l<6; l++){
      const float* Wq = Wqkv + (size_t)l*256*768;
      const float* Wl = Wo   + (size_t)l*256*256;
      const float* W1 = Wff1 + (size_t)l*256*1024;
      const float* W2 = Wff2 + (size_t)l*1024*256;

      ln_v2<<<2048, 256, 0, stream>>>(zf, ln1g+l*256, ln1b+l*256, hb);
      for (int c=0; c<4; c++){
        float* hrows = hb + (size_t)c*2048*256;
        gemm_mfma<0,0,0><<<dim3(6,16), 256, 0, stream>>>(hrows, nullptr, Wq, nullptr, nullptr,
                                                         bqkv+l*768, nullptr, scratch, nullptr, 768, 256);
        attn_v8<<<dim3(4,8,2), 1024, 0, stream>>>(scratch, hrows);
      }
      gemm_mfma<0,0,2><<<dim3(2,64), 256, 0, stream>>>(hb, nullptr, Wl, nullptr, nullptr,
                                                       bo+l*256, zf, zf, nullptr, 256, 256);
      ln_v2<<<2048, 256, 0, stream>>>(zf, ln2g+l*256, ln2b+l*256, hb);
      for (int c=0; c<4; c++){
        float* hrows = hb + (size_t)c*2048*256;
        float* zrows = zf + (size_t)c*2048*256;
        gemm_mfma<0,0,1><<<dim3(8,16), 256, 0, stream>>>(hrows, nullptr, W1, nullptr, nullptr,
                                                         bff1+l*1024, nullptr, scratch, nullptr, 1024, 256);
        gemm_mfma<0,0,2><<<dim3(2,16), 256, 0, stream>>>(scratch, nullptr, W2, nullptr, nullptr,
                                                         bff2+l*256, zrows, zrows, nullptr, 256, 1024);
      }
    }
  }
}

// Round 15
// 797.478 us; speedup vs baseline: 1.1138x; 1.0291x over previous
//
#include <hip/hip_runtime.h>

typedef short short8 __attribute__((ext_vector_type(8)));
typedef float f32x4 __attribute__((ext_vector_type(4)));
typedef unsigned short u16x4 __attribute__((ext_vector_type(4)));
typedef unsigned short u16x8 __attribute__((ext_vector_type(8)));

// f32 -> bf16 bits (round-to-nearest-even; finite inputs only)
__device__ __forceinline__ unsigned short f2bf(float x){
  unsigned int u = __float_as_uint(x);
  u = u + 0x7FFFu + ((u >> 16) & 1u);
  return (unsigned short)(u >> 16);
}
__device__ __forceinline__ float bf2f(unsigned short h){
  return __uint_as_float(((unsigned int)h) << 16);
}
// truncation split: hi = trunc16(x), lo = RNE(x - hi). |err| <= 2^-17 |x|.
__device__ __forceinline__ void tsplit(float x, unsigned short& h, unsigned short& l){
  unsigned int u = __float_as_uint(x);
  h = (unsigned short)(u >> 16);
  l = f2bf(x - __uint_as_float(u & 0xFFFF0000u));
}

// ---------------------------------------------------------------- convt
// One-time: split f32 weights into bf16 hi/lo planes AND transpose to [N][K]
// so GEMM B-staging becomes pure vectorized copies (round-14 counters: the
// in-GEMM transpose cost 2.6M LDS bank-conflict cycles/dispatch + 32 scalar
// stores per thread per K-tile). LDS-tiled 32k x 64n transpose.
// src: [L][K][N] f32 (blockIdx.z = layer); dst: [L][N][K] u16 planes.
__global__ __launch_bounds__(256) void convt(
    const float* __restrict__ S, unsigned short* __restrict__ Dh,
    unsigned short* __restrict__ Dl, int K, int N)
{
  __shared__ unsigned short th[64][33];
  __shared__ unsigned short tl[64][33];
  const int l = blockIdx.z;
  const int k0 = blockIdx.y*32, n0 = blockIdx.x*64;
  const float* src = S + (size_t)l*K*N;
  unsigned short* dh = Dh + (size_t)l*N*K;
  unsigned short* dl = Dl + (size_t)l*N*K;
  const int tid = threadIdx.x;
  #pragma unroll
  for (int p=0;p<2;p++){
    int i = tid + p*256;            // 0..511 float4s
    int k = i >> 4;                 // 0..31
    int n4 = (i & 15) * 4;          // 0..60
    float4 v = *(const float4*)&src[(size_t)(k0+k)*N + n0 + n4];
    float xs[4] = {v.x,v.y,v.z,v.w};
    #pragma unroll
    for (int e=0;e<4;e++){
      unsigned short hh,ll; tsplit(xs[e],hh,ll);
      th[n4+e][k]=hh; tl[n4+e][k]=ll;
    }
  }
  __syncthreads();
  #pragma unroll
  for (int p=0;p<2;p++){
    int i = tid + p*256;            // 0..511 u16x4s
    int n = i >> 3;                 // 0..63
    int k4 = (i & 7) * 4;           // 0..28
    u16x4 h, l_;
    #pragma unroll
    for (int e=0;e<4;e++){ h[e]=th[n][k4+e]; l_[e]=tl[n][k4+e]; }
    *(u16x4*)&dh[(size_t)(n0+n)*K + k0 + k4] = h;
    *(u16x4*)&dl[(size_t)(n0+n)*K + k0 + k4] = l_;
  }
}

// ---------------------------------------------------------------- encoder stage 1
__global__ __launch_bounds__(256) void encoder_s1(
    const float* __restrict__ xc, const float* __restrict__ yc, const float* __restrict__ xt,
    const float* __restrict__ W1, const float* __restrict__ b1,
    float* __restrict__ hid)
{
  __shared__ float zin[10];
  int blk = blockIdx.x; int b = blk>>10; int t = blk & 1023;
  int tid = threadIdx.x;
  if (tid < 10){
    float v;
    if (tid < 8)      v = (t<512) ? xc[((size_t)b*512+t)*8+tid] : xt[((size_t)b*512+(t-512))*8+tid];
    else if (tid==8)  v = (t<512) ? yc[(size_t)b*512+t] : 0.f;
    else              v = (t<512) ? 0.f : 1.f;
    zin[tid]=v;
  }
  __syncthreads();
  float s = b1[tid];
  #pragma unroll
  for (int i=0;i<10;i++) s += zin[i]*W1[i*256+tid];
  hid[(size_t)blk*256 + tid] = fmaxf(s, 0.f);
}

// ---------------------------------------------------------------- layernorm (f32 out; fallback)
__global__ __launch_bounds__(256) void ln_v2(const float* __restrict__ z,
    const float* __restrict__ g, const float* __restrict__ be, float* __restrict__ h)
{
  const int row = blockIdx.x*4 + (threadIdx.x>>6);
  const int lane = threadIdx.x & 63;
  float4 x = *(const float4*)&z[(size_t)row*256 + lane*4];
  float s = (x.x+x.y)+(x.z+x.w);
  #pragma unroll
  for (int off=32; off; off>>=1) s += __shfl_xor(s, off);
  float mu = s * (1.f/256.f);
  float dx = x.x-mu, dy = x.y-mu, dz = x.z-mu, dw = x.w-mu;
  float v = (dx*dx+dy*dy)+(dz*dz+dw*dw);
  #pragma unroll
  for (int off=32; off; off>>=1) v += __shfl_xor(v, off);
  float r = rsqrtf(v*(1.f/256.f) + 1e-5f);
  float4 gv = *(const float4*)&g[lane*4];
  float4 bv = *(const float4*)&be[lane*4];
  float4 o;
  o.x = dx*r*gv.x + bv.x; o.y = dy*r*gv.y + bv.y;
  o.z = dz*r*gv.z + bv.z; o.w = dw*r*gv.w + bv.w;
  *(float4*)&h[(size_t)row*256 + lane*4] = o;
}

// ---------------------------------------------------------------- layernorm -> bf16 hi/lo planes
// Streaming producer does the split (round-13 lesson: elementwise work belongs
// in BW-bound streaming kernels, NOT in the GEMM staging critical path).
__global__ __launch_bounds__(256) void ln_v2b(const float* __restrict__ z,
    const float* __restrict__ g, const float* __restrict__ be,
    unsigned short* __restrict__ hh, unsigned short* __restrict__ hl)
{
  const int row = blockIdx.x*4 + (threadIdx.x>>6);
  const int lane = threadIdx.x & 63;
  float4 x = *(const float4*)&z[(size_t)row*256 + lane*4];
  float s = (x.x+x.y)+(x.z+x.w);
  #pragma unroll
  for (int off=32; off; off>>=1) s += __shfl_xor(s, off);
  float mu = s * (1.f/256.f);
  float dx = x.x-mu, dy = x.y-mu, dz = x.z-mu, dw = x.w-mu;
  float v = (dx*dx+dy*dy)+(dz*dz+dw*dw);
  #pragma unroll
  for (int off=32; off; off>>=1) v += __shfl_xor(v, off);
  float r = rsqrtf(v*(1.f/256.f) + 1e-5f);
  float4 gv = *(const float4*)&g[lane*4];
  float4 bv = *(const float4*)&be[lane*4];
  float o[4];
  o[0] = dx*r*gv.x + bv.x; o[1] = dy*r*gv.y + bv.y;
  o[2] = dz*r*gv.z + bv.z; o[3] = dw*r*gv.w + bv.w;
  u16x4 H, L;
  #pragma unroll
  for (int e=0;e<4;e++){ unsigned short a,b2; tsplit(o[e],a,b2); H[e]=a; L[e]=b2; }
  size_t off = (size_t)row*256 + lane*4;
  *(u16x4*)&hh[off] = H;
  *(u16x4*)&hl[off] = L;
}

// ---------------------------------------------------------------- gemm_mfma
// out = EPI(A @ B + bias). 128x128 block, 4 waves, split-bf16 MFMA.
// APRE: 0 = A f32 (trunc-split in kernel, 3-term)
//       1 = A bf16 single plane (2-term)
//       2 = A pre-split hi/lo planes (copy-stage, 3-term)
// BPRE: 0 = B f32 [K][N] (in-kernel split+transpose; fallback only)
//       1 = B pre-split AND pre-transposed [N][K] hi/lo planes ->
//           staging is 4x ds_write_b128 per thread, no scalar stores.
// EPI : 0 plain f32 ; 1 relu f32 ; 2 +resid f32 ; 3 relu -> bf16 out
// Frag layouts HW-verified rounds 7-14. No launch_bounds min-waves (R4/R5).
template<int APRE, int BPRE, int EPI>
__global__ __launch_bounds__(256) void gemm_mfma(
    const float* __restrict__ Af,
    const unsigned short* __restrict__ Abh, const unsigned short* __restrict__ Abl,
    const float* __restrict__ Bf,
    const unsigned short* __restrict__ Bth, const unsigned short* __restrict__ Btl,
    const float* __restrict__ bias, const float* __restrict__ resid,
    float* __restrict__ outf, unsigned short* __restrict__ outb,
    int N, int K)
{
  constexpr int LDR = 40;
  __shared__ unsigned short Ah[128*LDR];
  __shared__ unsigned short Al[(APRE==1)?8:(128*LDR)];
  __shared__ unsigned short Bh[128*LDR], Bl[128*LDR];

  const int tid = threadIdx.x;
  const int lane = tid & 63, wv = tid >> 6;
  const int wm0 = (wv >> 1) * 64, wn0 = (wv & 1) * 64;
  const int m0 = blockIdx.y * 128, n0 = blockIdx.x * 128;

  // A staging map: row sar, k-half sak
  const int sar = tid >> 1, sak = (tid & 1) * 16;
  const int cA = ((sar >> 3) & 3) << 3;
  // B staging map (BPRE==0 fallback): k-row sbk, n-quad sbn
  const int sbk = tid >> 3, sbn = (tid & 7) * 16;
  const int cB = ((sbn >> 4) & 3) << 3;
  // B staging map (BPRE==1 transposed planes): n-row sbn2, k-half sbk2
  const int sbn2 = tid >> 1, sbk2 = (tid & 1) * 16;
  const int cB2 = ((sbn2 >> 4) & 3) << 3;

  const float* Apf = nullptr; const unsigned short *Aph = nullptr, *Apl = nullptr;
  if constexpr (APRE==0) Apf = Af  + (size_t)(m0 + sar) * K + sak;
  else {
    Aph = Abh + (size_t)(m0 + sar) * K + sak;
    if constexpr (APRE==2) Apl = Abl + (size_t)(m0 + sar) * K + sak;
  }
  const float* Bpf = nullptr; const unsigned short *Bph2 = nullptr, *Bpl2 = nullptr;
  if constexpr (BPRE==0) Bpf = Bf + (size_t)sbk * N + n0 + sbn;
  else {
    Bph2 = Bth + (size_t)(n0 + sbn2) * K + sbk2;
    Bpl2 = Btl + (size_t)(n0 + sbn2) * K + sbk2;
  }

  const int rowb = lane & 15, kb = (lane >> 4) * 8;
  const int NT = K / 32;

  f32x4 acc[4][4] = {};
  float4 pa[4], pb[4];
  u16x4 qah[4], qal[4];
  u16x8 qb2h[2], qb2l[2];

  auto LOADT = [&](int t){
    #pragma unroll
    for (int g = 0; g < 4; ++g){
      if constexpr (APRE==0) pa[g] = *(const float4*)&Apf[t*32 + g*4];
      else {
        qah[g] = *(const u16x4*)&Aph[t*32 + g*4];
        if constexpr (APRE==2) qal[g] = *(const u16x4*)&Apl[t*32 + g*4];
      }
    }
    if constexpr (BPRE==0){
      #pragma unroll
      for (int g = 0; g < 4; ++g) pb[g] = *(const float4*)&Bpf[(size_t)t*32*N + g*4];
    } else {
      #pragma unroll
      for (int g = 0; g < 2; ++g){
        qb2h[g] = *(const u16x8*)&Bph2[t*32 + g*8];
        qb2l[g] = *(const u16x8*)&Bpl2[t*32 + g*8];
      }
    }
  };
  auto STAGE = [&](){
    #pragma unroll
    for (int g = 0; g < 4; ++g){
      int idx = sar * LDR + ((sak + g * 4) ^ cA);
      if constexpr (APRE==0){
        float xs[4] = {pa[g].x, pa[g].y, pa[g].z, pa[g].w};
        u16x4 h, l;
        #pragma unroll
        for (int e = 0; e < 4; ++e){ unsigned short hh, ll; tsplit(xs[e], hh, ll); h[e]=hh; l[e]=ll; }
        *(u16x4*)&Ah[idx] = h; *(u16x4*)&Al[idx] = l;
      } else if constexpr (APRE==1){
        *(u16x4*)&Ah[idx] = qah[g];
      } else {
        *(u16x4*)&Ah[idx] = qah[g];
        *(u16x4*)&Al[idx] = qal[g];
      }
    }
    if constexpr (BPRE==0){
      int kx = sbk ^ cB;
      #pragma unroll
      for (int g = 0; g < 4; ++g){
        float xs[4] = {pb[g].x, pb[g].y, pb[g].z, pb[g].w};
        #pragma unroll
        for (int e = 0; e < 4; ++e){
          int n = sbn + g * 4 + e;
          unsigned short hh, ll; tsplit(xs[e], hh, ll);
          Bh[n * LDR + kx] = hh; Bl[n * LDR + kx] = ll;
        }
      }
    } else {
      #pragma unroll
      for (int g = 0; g < 2; ++g){
        int idx = sbn2 * LDR + ((sbk2 + g*8) ^ cB2);
        *(u16x8*)&Bh[idx] = qb2h[g];
        *(u16x8*)&Bl[idx] = qb2l[g];
      }
    }
  };

  LOADT(0);
  STAGE();
  __syncthreads();

  for (int t = 0; t < NT; ++t){
    if (t + 1 < NT) LOADT(t + 1);
    short8 bh[4], bl[4];
    #pragma unroll
    for (int ct = 0; ct < 4; ++ct){
      int n = wn0 + ct * 16 + rowb;
      int idx = n * LDR + (kb ^ (((n >> 4) & 3) << 3));
      bh[ct] = *(const short8*)&Bh[idx];
      bl[ct] = *(const short8*)&Bl[idx];
    }
    #pragma unroll
    for (int rt = 0; rt < 4; ++rt){
      int r = wm0 + rt * 16 + rowb;
      int idx = r * LDR + (kb ^ (((r >> 3) & 3) << 3));
      short8 ah = *(const short8*)&Ah[idx];
      #pragma unroll
      for (int ct = 0; ct < 4; ++ct){
        acc[rt][ct] = __builtin_amdgcn_mfma_f32_16x16x32_bf16(ah, bh[ct], acc[rt][ct], 0, 0, 0);
        acc[rt][ct] = __builtin_amdgcn_mfma_f32_16x16x32_bf16(ah, bl[ct], acc[rt][ct], 0, 0, 0);
      }
      if constexpr (APRE!=1){
        short8 al = *(const short8*)&Al[idx];
        #pragma unroll
        for (int ct = 0; ct < 4; ++ct)
          acc[rt][ct] = __builtin_amdgcn_mfma_f32_16x16x32_bf16(al, bh[ct], acc[rt][ct], 0, 0, 0);
      }
    }
    if (t + 1 < NT){
      __syncthreads();
      STAGE();
      __syncthreads();
    }
  }

  // epilogue: C/D layout col=lane&15, row=(lane>>4)*4+q  (HW-verified)
  #pragma unroll
  for (int ct = 0; ct < 4; ++ct){
    int gc = n0 + wn0 + ct * 16 + rowb;
    float bv = bias[gc];
    #pragma unroll
    for (int rt = 0; rt < 4; ++rt){
      int gr0 = m0 + wm0 + rt * 16 + (lane >> 4) * 4;
      #pragma unroll
      for (int q = 0; q < 4; ++q){
        size_t off = (size_t)(gr0 + q) * N + gc;
        float v = acc[rt][ct][q] + bv;
        if constexpr (EPI == 1) v = fmaxf(v, 0.f);
        if constexpr (EPI == 2) v += resid[off];
        if constexpr (EPI == 3) outb[off] = f2bf(fmaxf(v, 0.f));
        else                    outf[off] = v;
      }
    }
  }
}

// ---------------------------------------------------------------- attention v8 (MFMA flash)
// 1024 threads, qc=4 (amortized staging), 2-term QK, 73 KB LDS.
// OPL: 0 = f32 output (fallback); 1 = bf16 hi/lo plane output (feeds proj's
// copy-stage A path). Frag layouts HW-verified rounds 7-14.
template<int OPL>
__global__ __launch_bounds__(1024) void attn_v8(
    const float* __restrict__ qkv, float* __restrict__ o,
    unsigned short* __restrict__ oh, unsigned short* __restrict__ ol)
{
  constexpr int LDK = 40;
  constexpr int LDV = 520;
  __shared__ unsigned short Khi[512*LDK];   // 40 KB
  __shared__ unsigned short Vt[32*LDV];     // 32.5 KB
  __shared__ float cbuf[16][16];

  const int tid = threadIdx.x;
  const int qc = blockIdx.x, h = blockIdx.y, b = blockIdx.z;
  const float* base = qkv + (size_t)b*1024*768;
  const int hoff = h*32;
  const float sc = 0.17677669529663687f;

  #pragma unroll
  for (int t = 0; t < 4; ++t){
    int i = tid + t*1024;
    int row = i >> 3, c4 = (i & 7) * 4;
    float4 kv = *(const float4*)&base[(size_t)row*768 + 256 + hoff + c4];
    float ks[4] = {kv.x, kv.y, kv.z, kv.w};
    u16x4 hk;
    #pragma unroll
    for (int e = 0; e < 4; ++e) hk[e] = f2bf(ks[e]);
    *(u16x4*)&Khi[row*LDK + c4] = hk;
    float4 vv = *(const float4*)&base[(size_t)row*768 + 512 + hoff + c4];
    float vs[4] = {vv.x, vv.y, vv.z, vv.w};
    #pragma unroll
    for (int e = 0; e < 4; ++e)
      Vt[(c4 + e)*LDV + row] = f2bf(vs[e]);
  }

  const int wv = tid >> 6, lane = tid & 63;
  const int g = lane >> 4, r = lane & 15;
  const int q0w = qc*256 + wv*16;

  short8 qh, ql;
  {
    const float* qp = &base[(size_t)(q0w + r)*768 + hoff + g*8];
    float4 a = *(const float4*)qp;
    float4 c = *(const float4*)(qp + 4);
    float xs[8] = {a.x*sc, a.y*sc, a.z*sc, a.w*sc, c.x*sc, c.y*sc, c.z*sc, c.w*sc};
    #pragma unroll
    for (int e = 0; e < 8; ++e){
      unsigned short hb_ = f2bf(xs[e]);
      qh[e] = (short)hb_;
      ql[e] = (short)f2bf(xs[e] - bf2f(hb_));
    }
  }
  __syncthreads();

  float m = -1e30f, l = 0.f;
  f32x4 O0 = {0.f,0.f,0.f,0.f}, O1 = {0.f,0.f,0.f,0.f};

  for (int st = 0; st < 16; ++st){
    int key0 = st*32 + (r >> 2)*8 + (r & 3);
    short8 ah0 = *(const short8*)&Khi[key0*LDK + g*8];
    short8 ah1 = *(const short8*)&Khi[(key0+4)*LDK + g*8];
    f32x4 s0 = {0.f,0.f,0.f,0.f}, s1 = {0.f,0.f,0.f,0.f};
    s0 = __builtin_amdgcn_mfma_f32_16x16x32_bf16(ah0, qh, s0, 0,0,0);
    s0 = __builtin_amdgcn_mfma_f32_16x16x32_bf16(ah0, ql, s0, 0,0,0);
    s1 = __builtin_amdgcn_mfma_f32_16x16x32_bf16(ah1, qh, s1, 0,0,0);
    s1 = __builtin_amdgcn_mfma_f32_16x16x32_bf16(ah1, ql, s1, 0,0,0);
    float pv[8] = {s0[0],s0[1],s0[2],s0[3], s1[0],s1[1],s1[2],s1[3]};
    float tm = pv[0];
    #pragma unroll
    for (int j = 1; j < 8; ++j) tm = fmaxf(tm, pv[j]);
    tm = fmaxf(tm, __shfl_xor(tm, 16));
    tm = fmaxf(tm, __shfl_xor(tm, 32));
    float mn = fmaxf(m, tm);
    float ts = 0.f;
    #pragma unroll
    for (int j = 0; j < 8; ++j){ pv[j] = __expf(pv[j] - mn); ts += pv[j]; }
    ts += __shfl_xor(ts, 16);
    ts += __shfl_xor(ts, 32);
    if (__any(mn > m)){
      float corr = __expf(m - mn);
      if (lane < 16) cbuf[wv][lane] = corr;
      asm volatile("s_waitcnt lgkmcnt(0)" ::: "memory");
      f32x4 cf = *(const f32x4*)&cbuf[wv][g*4];
      #pragma unroll
      for (int j = 0; j < 4; ++j){ O0[j] *= cf[j]; O1[j] *= cf[j]; }
      l *= corr;
      m = mn;
    }
    l += ts;
    short8 pa;
    #pragma unroll
    for (int j = 0; j < 8; ++j) pa[j] = (short)f2bf(pv[j]);
    short8 v0 = *(const short8*)&Vt[(size_t)r*LDV + st*32 + g*8];
    short8 v1 = *(const short8*)&Vt[(size_t)(r+16)*LDV + st*32 + g*8];
    O0 = __builtin_amdgcn_mfma_f32_16x16x32_bf16(pa, v0, O0, 0,0,0);
    O1 = __builtin_amdgcn_mfma_f32_16x16x32_bf16(pa, v1, O1, 0,0,0);
  }

  // ---- self-attend tile (targets only): diagonal-masked, K/V from global
  if (qc >= 2){
    const float* kp = &base[(size_t)(q0w + r)*768 + 256 + hoff + g*8];
    float4 a = *(const float4*)kp;
    float4 c = *(const float4*)(kp + 4);
    float xs[8] = {a.x, a.y, a.z, a.w, c.x, c.y, c.z, c.w};
    short8 kh8;
    #pragma unroll
    for (int e = 0; e < 8; ++e) kh8[e] = (short)f2bf(xs[e]);
    f32x4 s = {0.f,0.f,0.f,0.f};
    s = __builtin_amdgcn_mfma_f32_16x16x32_bf16(kh8, qh, s, 0,0,0);
    s = __builtin_amdgcn_mfma_f32_16x16x32_bf16(kh8, ql, s, 0,0,0);
    float pv[8] = {0.f,0.f,0.f,0.f,0.f,0.f,0.f,0.f};
    float tm = -1e30f;
    #pragma unroll
    for (int j = 0; j < 4; ++j){
      bool al_ = (g*4 + j) == r;
      tm = fmaxf(tm, al_ ? s[j] : -1e30f);
    }
    tm = fmaxf(tm, __shfl_xor(tm, 16));
    tm = fmaxf(tm, __shfl_xor(tm, 32));
    float mn = fmaxf(m, tm);
    float ts = 0.f;
    #pragma unroll
    for (int j = 0; j < 4; ++j){
      bool al_ = (g*4 + j) == r;
      pv[j] = al_ ? __expf(s[j] - mn) : 0.f;
      ts += pv[j];
    }
    ts += __shfl_xor(ts, 16);
    ts += __shfl_xor(ts, 32);
    if (__any(mn > m)){
      float corr = __expf(m - mn);
      if (lane < 16) cbuf[wv][lane] = corr;
      asm volatile("s_waitcnt lgkmcnt(0)" ::: "memory");
      f32x4 cf = *(const f32x4*)&cbuf[wv][g*4];
      #pragma unroll
      for (int j = 0; j < 4; ++j){ O0[j] *= cf[j]; O1[j] *= cf[j]; }
      l *= corr;
      m = mn;
    }
    l += ts;
    short8 pa, v0, v1;
    #pragma unroll
    for (int j = 0; j < 8; ++j) pa[j] = (short)f2bf(pv[j]);
    #pragma unroll
    for (int j = 0; j < 4; ++j){
      const float* vp = &base[(size_t)(q0w + g*4 + j)*768 + 512 + hoff];
      v0[j] = (short)f2bf(vp[r]);
      v1[j] = (short)f2bf(vp[r + 16]);
      v0[j+4] = 0; v1[j+4] = 0;
    }
    O0 = __builtin_amdgcn_mfma_f32_16x16x32_bf16(pa, v0, O0, 0,0,0);
    O1 = __builtin_amdgcn_mfma_f32_16x16x32_bf16(pa, v1, O1, 0,0,0);
  }

  float inv = 1.f / l;
  if (lane < 16) cbuf[wv][lane] = inv;
  asm volatile("s_waitcnt lgkmcnt(0)" ::: "memory");
  f32x4 iv = *(const f32x4*)&cbuf[wv][g*4];
  if constexpr (OPL==0){
    float* op = o + ((size_t)b*1024 + q0w + g*4)*256 + hoff;
    #pragma unroll
    for (int j = 0; j < 4; ++j){
      op[(size_t)j*256 + r]      = O0[j] * iv[j];
      op[(size_t)j*256 + r + 16] = O1[j] * iv[j];
    }
  } else {
    size_t ob = ((size_t)b*1024 + q0w + g*4)*256 + hoff;
    #pragma unroll
    for (int j = 0; j < 4; ++j){
      unsigned short hh, ll;
      tsplit(O0[j]*iv[j], hh, ll);
      oh[ob + (size_t)j*256 + r] = hh;  ol[ob + (size_t)j*256 + r] = ll;
      tsplit(O1[j]*iv[j], hh, ll);
      oh[ob + (size_t)j*256 + r + 16] = hh;  ol[ob + (size_t)j*256 + r + 16] = ll;
    }
  }
}

// ---------------------------------------------------------------- launch
extern "C" void kernel_launch(void* const* d_in, const int* in_sizes, int n_in,
                              void* d_out, int out_size, void* d_ws, size_t ws_size,
                              hipStream_t stream)
{
  (void)in_sizes; (void)n_in; (void)out_size;
  const float* xc   = (const float*)d_in[0];
  const float* yc   = (const float*)d_in[1];
  const float* xt   = (const float*)d_in[2];
  const float* eW1  = (const float*)d_in[3];
  const float* eb1  = (const float*)d_in[4];
  const float* eW2  = (const float*)d_in[5];
  const float* eb2  = (const float*)d_in[6];
  const float* Wqkv = (const float*)d_in[7];
  const float* bqkv = (const float*)d_in[8];
  const float* Wo   = (const float*)d_in[9];
  const float* bo   = (const float*)d_in[10];
  const float* ln1g = (const float*)d_in[11];
  const float* ln1b = (const float*)d_in[12];
  const float* ln2g = (const float*)d_in[13];
  const float* ln2b = (const float*)d_in[14];
  const float* Wff1 = (const float*)d_in[15];
  const float* bff1 = (const float*)d_in[16];
  const float* Wff2 = (const float*)d_in[17];
  const float* bff2 = (const float*)d_in[18];

  float* zf = (float*)d_out;            // residual stream [8][1024][256] f32 = 8 MB
  char* ws = (char*)d_ws;

  const size_t MiB = 1024*1024;
  const bool hugews = (ws_size == 0) || (ws_size >= 64*MiB);   // observed ws = 256 MiB

  if (hugews){
    // layout: [0,8) LN planes; [8,32) scratch (qkv f32 24 / ffh bf16 16);
    //         [32,~50.3) transposed weight planes; [52,60) attn-out planes.
    unsigned short* lnh = (unsigned short*)ws;                      // 4 MiB
    unsigned short* lnl = lnh + 4*MiB/2;
    float*          scratch = (float*)(ws + 8*MiB);
    unsigned short* ffh_b   = (unsigned short*)scratch;
    unsigned short* W = (unsigned short*)(ws + 32*MiB);
    unsigned short* qkvTh = W;                   // 6*196608 per plane
    unsigned short* qkvTl = W + 1179648;
    unsigned short* woTh  = W + 2359296;         // 6*65536
    unsigned short* woTl  = W + 2752512;
    unsigned short* w1Th  = W + 3145728;         // 6*262144
    unsigned short* w1Tl  = W + 4718592;
    unsigned short* w2Th  = W + 6291456;
    unsigned short* w2Tl  = W + 7864320;
    unsigned short* e2Th  = W + 9437184;         // 65536
    unsigned short* e2Tl  = W + 9502720;
    unsigned short* aoh = (unsigned short*)(ws + 52*MiB);           // 4 MiB
    unsigned short* aol = aoh + 4*MiB/2;

    // one-time: split + transpose all weights ([K][N] f32 -> [N][K] bf16 hi/lo)
    convt<<<dim3(12,8,6), 256, 0, stream>>>(Wqkv, qkvTh, qkvTl, 256, 768);
    convt<<<dim3(4,8,6),  256, 0, stream>>>(Wo,   woTh,  woTl,  256, 256);
    convt<<<dim3(16,8,6), 256, 0, stream>>>(Wff1, w1Th,  w1Tl,  256, 1024);
    convt<<<dim3(4,32,6), 256, 0, stream>>>(Wff2, w2Th,  w2Tl,  1024, 256);
    convt<<<dim3(4,8,1),  256, 0, stream>>>(eW2,  e2Th,  e2Tl,  256, 256);

    encoder_s1<<<8192, 256, 0, stream>>>(xc, yc, xt, eW1, eb1, scratch);
    gemm_mfma<0,1,0><<<dim3(2,64), 256, 0, stream>>>(scratch, nullptr, nullptr,
                                                     nullptr, e2Th, e2Tl,
                                                     eb2, nullptr, zf, nullptr, 256, 256);

    for (int l=0; l<6; l++){
      unsigned short* qh_ = qkvTh + (size_t)l*196608;
      unsigned short* ql_ = qkvTl + (size_t)l*196608;
      unsigned short* oh_ = woTh  + (size_t)l*65536;
      unsigned short* olw = woTl  + (size_t)l*65536;
      unsigned short* f1h = w1Th  + (size_t)l*262144;
      unsigned short* f1l = w1Tl  + (size_t)l*262144;
      unsigned short* f2h = w2Th  + (size_t)l*262144;
      unsigned short* f2l = w2Tl  + (size_t)l*262144;

      ln_v2b<<<2048, 256, 0, stream>>>(zf, ln1g+l*256, ln1b+l*256, lnh, lnl);
      gemm_mfma<2,1,0><<<dim3(6,64), 256, 0, stream>>>(nullptr, lnh, lnl,
                                                       nullptr, qh_, ql_,
                                                       bqkv+l*768, nullptr, scratch, nullptr, 768, 256);
      attn_v8<1><<<dim3(4,8,8), 1024, 0, stream>>>(scratch, nullptr, aoh, aol);
      gemm_mfma<2,1,2><<<dim3(2,64), 256, 0, stream>>>(nullptr, aoh, aol,
                                                       nullptr, oh_, olw,
                                                       bo+l*256, zf, zf, nullptr, 256, 256);
      ln_v2b<<<2048, 256, 0, stream>>>(zf, ln2g+l*256, ln2b+l*256, lnh, lnl);
      gemm_mfma<2,1,3><<<dim3(8,64), 256, 0, stream>>>(nullptr, lnh, lnl,
                                                       nullptr, f1h, f1l,
                                                       bff1+l*1024, nullptr, nullptr, ffh_b, 1024, 256);
      gemm_mfma<1,1,2><<<dim3(2,64), 256, 0, stream>>>(nullptr, ffh_b, nullptr,
                                                       nullptr, f2h, f2l,
                                                       bff2+l*256, zf, zf, nullptr, 256, 1024);
    }
  } else {
    // conservative fallback: all-f32 path (in-kernel split), chunked scratch
    float* hb      = (float*)(ws);
    float* scratch = (float*)(ws + 8*MiB);
    encoder_s1<<<8192, 256, 0, stream>>>(xc, yc, xt, eW1, eb1, hb);
    gemm_mfma<0,0,0><<<dim3(2,64), 256, 0, stream>>>(hb, nullptr, nullptr, eW2, nullptr, nullptr,
                                                     eb2, nullptr, zf, nullptr, 256, 256);
    for (int l=0; l<6; l++){
      const float* Wq = Wqkv + (size_t)l*256*768;
      const float* Wl = Wo   + (size_t)l*256*256;
      const float* W1 = Wff1 + (size_t)l*256*1024;
      const float* W2 = Wff2 + (size_t)l*1024*256;

      ln_v2<<<2048, 256, 0, stream>>>(zf, ln1g+l*256, ln1b+l*256, hb);
      for (int c=0; c<4; c++){
        float* hrows = hb + (size_t)c*2048*256;
        gemm_mfma<0,0,0><<<dim3(6,16), 256, 0, stream>>>(hrows, nullptr, nullptr, Wq, nullptr, nullptr,
                                                         bqkv+l*768, nullptr, scratch, nullptr, 768, 256);
        attn_v8<0><<<dim3(4,8,2), 1024, 0, stream>>>(scratch, hrows, nullptr, nullptr);
      }
      gemm_mfma<0,0,2><<<dim3(2,64), 256, 0, stream>>>(hb, nullptr, nullptr, Wl, nullptr, nullptr,
                                                       bo+l*256, zf, zf, nullptr, 256, 256);
      ln_v2<<<2048, 256, 0, stream>>>(zf, ln2g+l*256, ln2b+l*256, hb);
      for (int c=0; c<4; c++){
        float* hrows = hb + (size_t)c*2048*256;
        float* zrows = zf + (size_t)c*2048*256;
        gemm_mfma<0,0,1><<<dim3(8,16), 256, 0, stream>>>(hrows, nullptr, nullptr, W1, nullptr, nullptr,
                                                         bff1+l*1024, nullptr, scratch, nullptr, 1024, 256);
        gemm_mfma<0,0,2><<<dim3(2,16), 256, 0, stream>>>(scratch, nullptr, nullptr, W2, nullptr, nullptr,
                                                         bff2+l*256, zrows, zrows, nullptr, 256, 1024);
      }
    }
  }
}

// Round 16
// 759.670 us; speedup vs baseline: 1.1692x; 1.0498x over previous
//
#include <hip/hip_runtime.h>

typedef short short8 __attribute__((ext_vector_type(8)));
typedef float f32x4 __attribute__((ext_vector_type(4)));
typedef unsigned short u16x4 __attribute__((ext_vector_type(4)));
typedef unsigned short u16x8 __attribute__((ext_vector_type(8)));

// f32 -> bf16 bits (round-to-nearest-even; finite inputs only)
__device__ __forceinline__ unsigned short f2bf(float x){
  unsigned int u = __float_as_uint(x);
  u = u + 0x7FFFu + ((u >> 16) & 1u);
  return (unsigned short)(u >> 16);
}
__device__ __forceinline__ float bf2f(unsigned short h){
  return __uint_as_float(((unsigned int)h) << 16);
}
// truncation split: hi = trunc16(x), lo = RNE(x - hi). |err| <= 2^-17 |x|.
__device__ __forceinline__ void tsplit(float x, unsigned short& h, unsigned short& l){
  unsigned int u = __float_as_uint(x);
  h = (unsigned short)(u >> 16);
  l = f2bf(x - __uint_as_float(u & 0xFFFF0000u));
}

// ---------------------------------------------------------------- convt
// One-time: split f32 weights into bf16 hi/lo planes AND transpose to [N][K]
// so GEMM B-staging is pure vectorized copies (round-14/15 verified).
__global__ __launch_bounds__(256) void convt(
    const float* __restrict__ S, unsigned short* __restrict__ Dh,
    unsigned short* __restrict__ Dl, int K, int N)
{
  __shared__ unsigned short th[64][33];
  __shared__ unsigned short tl[64][33];
  const int l = blockIdx.z;
  const int k0 = blockIdx.y*32, n0 = blockIdx.x*64;
  const float* src = S + (size_t)l*K*N;
  unsigned short* dh = Dh + (size_t)l*N*K;
  unsigned short* dl = Dl + (size_t)l*N*K;
  const int tid = threadIdx.x;
  #pragma unroll
  for (int p=0;p<2;p++){
    int i = tid + p*256;
    int k = i >> 4;
    int n4 = (i & 15) * 4;
    float4 v = *(const float4*)&src[(size_t)(k0+k)*N + n0 + n4];
    float xs[4] = {v.x,v.y,v.z,v.w};
    #pragma unroll
    for (int e=0;e<4;e++){
      unsigned short hh,ll; tsplit(xs[e],hh,ll);
      th[n4+e][k]=hh; tl[n4+e][k]=ll;
    }
  }
  __syncthreads();
  #pragma unroll
  for (int p=0;p<2;p++){
    int i = tid + p*256;
    int n = i >> 3;
    int k4 = (i & 7) * 4;
    u16x4 h, l_;
    #pragma unroll
    for (int e=0;e<4;e++){ h[e]=th[n][k4+e]; l_[e]=tl[n][k4+e]; }
    *(u16x4*)&dh[(size_t)(n0+n)*K + k0 + k4] = h;
    *(u16x4*)&dl[(size_t)(n0+n)*K + k0 + k4] = l_;
  }
}

// ---------------------------------------------------------------- encoder stage 1
__global__ __launch_bounds__(256) void encoder_s1(
    const float* __restrict__ xc, const float* __restrict__ yc, const float* __restrict__ xt,
    const float* __restrict__ W1, const float* __restrict__ b1,
    float* __restrict__ hid)
{
  __shared__ float zin[10];
  int blk = blockIdx.x; int b = blk>>10; int t = blk & 1023;
  int tid = threadIdx.x;
  if (tid < 10){
    float v;
    if (tid < 8)      v = (t<512) ? xc[((size_t)b*512+t)*8+tid] : xt[((size_t)b*512+(t-512))*8+tid];
    else if (tid==8)  v = (t<512) ? yc[(size_t)b*512+t] : 0.f;
    else              v = (t<512) ? 0.f : 1.f;
    zin[tid]=v;
  }
  __syncthreads();
  float s = b1[tid];
  #pragma unroll
  for (int i=0;i<10;i++) s += zin[i]*W1[i*256+tid];
  hid[(size_t)blk*256 + tid] = fmaxf(s, 0.f);
}

// ---------------------------------------------------------------- layernorm (f32 out; fallback)
__global__ __launch_bounds__(256) void ln_v2(const float* __restrict__ z,
    const float* __restrict__ g, const float* __restrict__ be, float* __restrict__ h)
{
  const int row = blockIdx.x*4 + (threadIdx.x>>6);
  const int lane = threadIdx.x & 63;
  float4 x = *(const float4*)&z[(size_t)row*256 + lane*4];
  float s = (x.x+x.y)+(x.z+x.w);
  #pragma unroll
  for (int off=32; off; off>>=1) s += __shfl_xor(s, off);
  float mu = s * (1.f/256.f);
  float dx = x.x-mu, dy = x.y-mu, dz = x.z-mu, dw = x.w-mu;
  float v = (dx*dx+dy*dy)+(dz*dz+dw*dw);
  #pragma unroll
  for (int off=32; off; off>>=1) v += __shfl_xor(v, off);
  float r = rsqrtf(v*(1.f/256.f) + 1e-5f);
  float4 gv = *(const float4*)&g[lane*4];
  float4 bv = *(const float4*)&be[lane*4];
  float4 o;
  o.x = dx*r*gv.x + bv.x; o.y = dy*r*gv.y + bv.y;
  o.z = dz*r*gv.z + bv.z; o.w = dw*r*gv.w + bv.w;
  *(float4*)&h[(size_t)row*256 + lane*4] = o;
}

// ---------------------------------------------------------------- layernorm -> bf16 hi/lo planes
__global__ __launch_bounds__(256) void ln_v2b(const float* __restrict__ z,
    const float* __restrict__ g, const float* __restrict__ be,
    unsigned short* __restrict__ hh, unsigned short* __restrict__ hl)
{
  const int row = blockIdx.x*4 + (threadIdx.x>>6);
  const int lane = threadIdx.x & 63;
  float4 x = *(const float4*)&z[(size_t)row*256 + lane*4];
  float s = (x.x+x.y)+(x.z+x.w);
  #pragma unroll
  for (int off=32; off; off>>=1) s += __shfl_xor(s, off);
  float mu = s * (1.f/256.f);
  float dx = x.x-mu, dy = x.y-mu, dz = x.z-mu, dw = x.w-mu;
  float v = (dx*dx+dy*dy)+(dz*dz+dw*dw);
  #pragma unroll
  for (int off=32; off; off>>=1) v += __shfl_xor(v, off);
  float r = rsqrtf(v*(1.f/256.f) + 1e-5f);
  float4 gv = *(const float4*)&g[lane*4];
  float4 bv = *(const float4*)&be[lane*4];
  float o[4];
  o[0] = dx*r*gv.x + bv.x; o[1] = dy*r*gv.y + bv.y;
  o[2] = dz*r*gv.z + bv.z; o[3] = dw*r*gv.w + bv.w;
  u16x4 H, L;
  #pragma unroll
  for (int e=0;e<4;e++){ unsigned short a,b2; tsplit(o[e],a,b2); H[e]=a; L[e]=b2; }
  size_t off = (size_t)row*256 + lane*4;
  *(u16x4*)&hh[off] = H;
  *(u16x4*)&hl[off] = L;
}

// ---------------------------------------------------------------- gemm_mfma
// out = EPI(A @ B + bias). BM=128 x BN block, 4 waves, split-bf16 MFMA.
// BN: 128 -> waves 2x2 of 64x64 (acc[4][4]); 64 -> waves 2x2 of 64x32
// (acc[4][2]). Round-16: BN=64 for the N=256 GEMMs (proj/ff2/enc) and qkv ->
// grids 256 = 1/CU (were 128 = half idle) and 768 = 3/CU (was 1.5, tail).
// APRE: 0 = A f32 (trunc-split in kernel, 3-term)
//       1 = A bf16 single plane (2-term)
//       2 = A pre-split hi/lo planes (copy-stage, 3-term)
// BPRE: 0 = B f32 [K][N] (in-kernel split+transpose; fallback only, BN=128)
//       1 = B pre-split AND pre-transposed [N][K] hi/lo planes (pure copy)
// EPI : 0 plain f32 ; 1 relu f32 ; 2 +resid f32 ; 3 relu -> bf16 out
// Frag layouts HW-verified rounds 7-15. No launch_bounds min-waves (R4/R5).
template<int APRE, int BPRE, int EPI, int BN>
__global__ __launch_bounds__(256) void gemm_mfma(
    const float* __restrict__ Af,
    const unsigned short* __restrict__ Abh, const unsigned short* __restrict__ Abl,
    const float* __restrict__ Bf,
    const unsigned short* __restrict__ Bth, const unsigned short* __restrict__ Btl,
    const float* __restrict__ bias, const float* __restrict__ resid,
    float* __restrict__ outf, unsigned short* __restrict__ outb,
    int N, int K)
{
  constexpr int LDR = 40;
  constexpr int TC  = BN/32;           // col-tiles per wave (4 or 2)
  constexpr int NB8 = BN/64;           // u16x8 B-loads per thread (2 or 1)
  __shared__ unsigned short Ah[128*LDR];
  __shared__ unsigned short Al[(APRE==1)?8:(128*LDR)];
  __shared__ unsigned short Bh[BN*LDR], Bl[BN*LDR];

  const int tid = threadIdx.x;
  const int lane = tid & 63, wv = tid >> 6;
  const int wm0 = (wv >> 1) * 64, wn0 = (wv & 1) * (BN/2);
  const int m0 = blockIdx.y * 128, n0 = blockIdx.x * BN;

  // A staging map: row sar, k-half sak
  const int sar = tid >> 1, sak = (tid & 1) * 16;
  const int cA = ((sar >> 3) & 3) << 3;
  // B staging map (BPRE==0 fallback, BN==128 only): k-row sbk, n-quad sbn
  const int sbk = tid >> 3, sbn = (tid & 7) * 16;
  const int cB = ((sbn >> 4) & 3) << 3;
  // B staging map (BPRE==1 transposed planes)
  const int sbn2 = (BN==128) ? (tid >> 1) : (tid >> 2);
  const int sbk2 = (BN==128) ? ((tid & 1) * 16) : ((tid & 3) * 8);
  const int cB2 = ((sbn2 >> 4) & 3) << 3;

  const float* Apf = nullptr; const unsigned short *Aph = nullptr, *Apl = nullptr;
  if constexpr (APRE==0) Apf = Af  + (size_t)(m0 + sar) * K + sak;
  else {
    Aph = Abh + (size_t)(m0 + sar) * K + sak;
    if constexpr (APRE==2) Apl = Abl + (size_t)(m0 + sar) * K + sak;
  }
  const float* Bpf = nullptr; const unsigned short *Bph2 = nullptr, *Bpl2 = nullptr;
  if constexpr (BPRE==0) Bpf = Bf + (size_t)sbk * N + n0 + sbn;
  else {
    Bph2 = Bth + (size_t)(n0 + sbn2) * K + sbk2;
    Bpl2 = Btl + (size_t)(n0 + sbn2) * K + sbk2;
  }

  const int rowb = lane & 15, kb = (lane >> 4) * 8;
  const int NT = K / 32;

  f32x4 acc[4][TC] = {};
  float4 pa[4], pb[4];
  u16x4 qah[4], qal[4];
  u16x8 qb2h[2], qb2l[2];

  auto LOADT = [&](int t){
    #pragma unroll
    for (int g = 0; g < 4; ++g){
      if constexpr (APRE==0) pa[g] = *(const float4*)&Apf[t*32 + g*4];
      else {
        qah[g] = *(const u16x4*)&Aph[t*32 + g*4];
        if constexpr (APRE==2) qal[g] = *(const u16x4*)&Apl[t*32 + g*4];
      }
    }
    if constexpr (BPRE==0){
      #pragma unroll
      for (int g = 0; g < 4; ++g) pb[g] = *(const float4*)&Bpf[(size_t)t*32*N + g*4];
    } else {
      #pragma unroll
      for (int g = 0; g < NB8; ++g){
        qb2h[g] = *(const u16x8*)&Bph2[t*32 + g*8];
        qb2l[g] = *(const u16x8*)&Bpl2[t*32 + g*8];
      }
    }
  };
  auto STAGE = [&](){
    #pragma unroll
    for (int g = 0; g < 4; ++g){
      int idx = sar * LDR + ((sak + g * 4) ^ cA);
      if constexpr (APRE==0){
        float xs[4] = {pa[g].x, pa[g].y, pa[g].z, pa[g].w};
        u16x4 h, l;
        #pragma unroll
        for (int e = 0; e < 4; ++e){ unsigned short hh, ll; tsplit(xs[e], hh, ll); h[e]=hh; l[e]=ll; }
        *(u16x4*)&Ah[idx] = h; *(u16x4*)&Al[idx] = l;
      } else if constexpr (APRE==1){
        *(u16x4*)&Ah[idx] = qah[g];
      } else {
        *(u16x4*)&Ah[idx] = qah[g];
        *(u16x4*)&Al[idx] = qal[g];
      }
    }
    if constexpr (BPRE==0){
      int kx = sbk ^ cB;
      #pragma unroll
      for (int g = 0; g < 4; ++g){
        float xs[4] = {pb[g].x, pb[g].y, pb[g].z, pb[g].w};
        #pragma unroll
        for (int e = 0; e < 4; ++e){
          int n = sbn + g * 4 + e;
          unsigned short hh, ll; tsplit(xs[e], hh, ll);
          Bh[n * LDR + kx] = hh; Bl[n * LDR + kx] = ll;
        }
      }
    } else {
      #pragma unroll
      for (int g = 0; g < NB8; ++g){
        int idx = sbn2 * LDR + ((sbk2 + g*8) ^ cB2);
        *(u16x8*)&Bh[idx] = qb2h[g];
        *(u16x8*)&Bl[idx] = qb2l[g];
      }
    }
  };

  LOADT(0);
  STAGE();
  __syncthreads();

  for (int t = 0; t < NT; ++t){
    if (t + 1 < NT) LOADT(t + 1);
    short8 bh[TC], bl[TC];
    #pragma unroll
    for (int ct = 0; ct < TC; ++ct){
      int n = wn0 + ct * 16 + rowb;
      int idx = n * LDR + (kb ^ (((n >> 4) & 3) << 3));
      bh[ct] = *(const short8*)&Bh[idx];
      bl[ct] = *(const short8*)&Bl[idx];
    }
    #pragma unroll
    for (int rt = 0; rt < 4; ++rt){
      int r = wm0 + rt * 16 + rowb;
      int idx = r * LDR + (kb ^ (((r >> 3) & 3) << 3));
      short8 ah = *(const short8*)&Ah[idx];
      #pragma unroll
      for (int ct = 0; ct < TC; ++ct){
        acc[rt][ct] = __builtin_amdgcn_mfma_f32_16x16x32_bf16(ah, bh[ct], acc[rt][ct], 0, 0, 0);
        acc[rt][ct] = __builtin_amdgcn_mfma_f32_16x16x32_bf16(ah, bl[ct], acc[rt][ct], 0, 0, 0);
      }
      if constexpr (APRE!=1){
        short8 al = *(const short8*)&Al[idx];
        #pragma unroll
        for (int ct = 0; ct < TC; ++ct)
          acc[rt][ct] = __builtin_amdgcn_mfma_f32_16x16x32_bf16(al, bh[ct], acc[rt][ct], 0, 0, 0);
      }
    }
    if (t + 1 < NT){
      __syncthreads();
      STAGE();
      __syncthreads();
    }
  }

  // epilogue: C/D layout col=lane&15, row=(lane>>4)*4+q  (HW-verified)
  #pragma unroll
  for (int ct = 0; ct < TC; ++ct){
    int gc = n0 + wn0 + ct * 16 + rowb;
    float bv = bias[gc];
    #pragma unroll
    for (int rt = 0; rt < 4; ++rt){
      int gr0 = m0 + wm0 + rt * 16 + (lane >> 4) * 4;
      #pragma unroll
      for (int q = 0; q < 4; ++q){
        size_t off = (size_t)(gr0 + q) * N + gc;
        float v = acc[rt][ct][q] + bv;
        if constexpr (EPI == 1) v = fmaxf(v, 0.f);
        if constexpr (EPI == 2) v += resid[off];
        if constexpr (EPI == 3) outb[off] = f2bf(fmaxf(v, 0.f));
        else                    outf[off] = v;
      }
    }
  }
}

// ---------------------------------------------------------------- attention v8 (MFMA flash)
// 1024 threads, qc=4 (amortized staging), 2-term QK, 73 KB LDS.
// OPL: 0 = f32 output (fallback); 1 = bf16 hi/lo plane output.
template<int OPL>
__global__ __launch_bounds__(1024) void attn_v8(
    const float* __restrict__ qkv, float* __restrict__ o,
    unsigned short* __restrict__ oh, unsigned short* __restrict__ ol)
{
  constexpr int LDK = 40;
  constexpr int LDV = 520;
  __shared__ unsigned short Khi[512*LDK];   // 40 KB
  __shared__ unsigned short Vt[32*LDV];     // 32.5 KB
  __shared__ float cbuf[16][16];

  const int tid = threadIdx.x;
  const int qc = blockIdx.x, h = blockIdx.y, b = blockIdx.z;
  const float* base = qkv + (size_t)b*1024*768;
  const int hoff = h*32;
  const float sc = 0.17677669529663687f;

  #pragma unroll
  for (int t = 0; t < 4; ++t){
    int i = tid + t*1024;
    int row = i >> 3, c4 = (i & 7) * 4;
    float4 kv = *(const float4*)&base[(size_t)row*768 + 256 + hoff + c4];
    float ks[4] = {kv.x, kv.y, kv.z, kv.w};
    u16x4 hk;
    #pragma unroll
    for (int e = 0; e < 4; ++e) hk[e] = f2bf(ks[e]);
    *(u16x4*)&Khi[row*LDK + c4] = hk;
    float4 vv = *(const float4*)&base[(size_t)row*768 + 512 + hoff + c4];
    float vs[4] = {vv.x, vv.y, vv.z, vv.w};
    #pragma unroll
    for (int e = 0; e < 4; ++e)
      Vt[(c4 + e)*LDV + row] = f2bf(vs[e]);
  }

  const int wv = tid >> 6, lane = tid & 63;
  const int g = lane >> 4, r = lane & 15;
  const int q0w = qc*256 + wv*16;

  short8 qh, ql;
  {
    const float* qp = &base[(size_t)(q0w + r)*768 + hoff + g*8];
    float4 a = *(const float4*)qp;
    float4 c = *(const float4*)(qp + 4);
    float xs[8] = {a.x*sc, a.y*sc, a.z*sc, a.w*sc, c.x*sc, c.y*sc, c.z*sc, c.w*sc};
    #pragma unroll
    for (int e = 0; e < 8; ++e){
      unsigned short hb_ = f2bf(xs[e]);
      qh[e] = (short)hb_;
      ql[e] = (short)f2bf(xs[e] - bf2f(hb_));
    }
  }
  __syncthreads();

  float m = -1e30f, l = 0.f;
  f32x4 O0 = {0.f,0.f,0.f,0.f}, O1 = {0.f,0.f,0.f,0.f};

  for (int st = 0; st < 16; ++st){
    int key0 = st*32 + (r >> 2)*8 + (r & 3);
    short8 ah0 = *(const short8*)&Khi[key0*LDK + g*8];
    short8 ah1 = *(const short8*)&Khi[(key0+4)*LDK + g*8];
    f32x4 s0 = {0.f,0.f,0.f,0.f}, s1 = {0.f,0.f,0.f,0.f};
    s0 = __builtin_amdgcn_mfma_f32_16x16x32_bf16(ah0, qh, s0, 0,0,0);
    s0 = __builtin_amdgcn_mfma_f32_16x16x32_bf16(ah0, ql, s0, 0,0,0);
    s1 = __builtin_amdgcn_mfma_f32_16x16x32_bf16(ah1, qh, s1, 0,0,0);
    s1 = __builtin_amdgcn_mfma_f32_16x16x32_bf16(ah1, ql, s1, 0,0,0);
    float pv[8] = {s0[0],s0[1],s0[2],s0[3], s1[0],s1[1],s1[2],s1[3]};
    float tm = pv[0];
    #pragma unroll
    for (int j = 1; j < 8; ++j) tm = fmaxf(tm, pv[j]);
    tm = fmaxf(tm, __shfl_xor(tm, 16));
    tm = fmaxf(tm, __shfl_xor(tm, 32));
    float mn = fmaxf(m, tm);
    float ts = 0.f;
    #pragma unroll
    for (int j = 0; j < 8; ++j){ pv[j] = __expf(pv[j] - mn); ts += pv[j]; }
    ts += __shfl_xor(ts, 16);
    ts += __shfl_xor(ts, 32);
    if (__any(mn > m)){
      float corr = __expf(m - mn);
      if (lane < 16) cbuf[wv][lane] = corr;
      asm volatile("s_waitcnt lgkmcnt(0)" ::: "memory");
      f32x4 cf = *(const f32x4*)&cbuf[wv][g*4];
      #pragma unroll
      for (int j = 0; j < 4; ++j){ O0[j] *= cf[j]; O1[j] *= cf[j]; }
      l *= corr;
      m = mn;
    }
    l += ts;
    short8 pa;
    #pragma unroll
    for (int j = 0; j < 8; ++j) pa[j] = (short)f2bf(pv[j]);
    short8 v0 = *(const short8*)&Vt[(size_t)r*LDV + st*32 + g*8];
    short8 v1 = *(const short8*)&Vt[(size_t)(r+16)*LDV + st*32 + g*8];
    O0 = __builtin_amdgcn_mfma_f32_16x16x32_bf16(pa, v0, O0, 0,0,0);
    O1 = __builtin_amdgcn_mfma_f32_16x16x32_bf16(pa, v1, O1, 0,0,0);
  }

  // ---- self-attend tile (targets only): diagonal-masked, K/V from global
  if (qc >= 2){
    const float* kp = &base[(size_t)(q0w + r)*768 + 256 + hoff + g*8];
    float4 a = *(const float4*)kp;
    float4 c = *(const float4*)(kp + 4);
    float xs[8] = {a.x, a.y, a.z, a.w, c.x, c.y, c.z, c.w};
    short8 kh8;
    #pragma unroll
    for (int e = 0; e < 8; ++e) kh8[e] = (short)f2bf(xs[e]);
    f32x4 s = {0.f,0.f,0.f,0.f};
    s = __builtin_amdgcn_mfma_f32_16x16x32_bf16(kh8, qh, s, 0,0,0);
    s = __builtin_amdgcn_mfma_f32_16x16x32_bf16(kh8, ql, s, 0,0,0);
    float pv[8] = {0.f,0.f,0.f,0.f,0.f,0.f,0.f,0.f};
    float tm = -1e30f;
    #pragma unroll
    for (int j = 0; j < 4; ++j){
      bool al_ = (g*4 + j) == r;
      tm = fmaxf(tm, al_ ? s[j] : -1e30f);
    }
    tm = fmaxf(tm, __shfl_xor(tm, 16));
    tm = fmaxf(tm, __shfl_xor(tm, 32));
    float mn = fmaxf(m, tm);
    float ts = 0.f;
    #pragma unroll
    for (int j = 0; j < 4; ++j){
      bool al_ = (g*4 + j) == r;
      pv[j] = al_ ? __expf(s[j] - mn) : 0.f;
      ts += pv[j];
    }
    ts += __shfl_xor(ts, 16);
    ts += __shfl_xor(ts, 32);
    if (__any(mn > m)){
      float corr = __expf(m - mn);
      if (lane < 16) cbuf[wv][lane] = corr;
      asm volatile("s_waitcnt lgkmcnt(0)" ::: "memory");
      f32x4 cf = *(const f32x4*)&cbuf[wv][g*4];
      #pragma unroll
      for (int j = 0; j < 4; ++j){ O0[j] *= cf[j]; O1[j] *= cf[j]; }
      l *= corr;
      m = mn;
    }
    l += ts;
    short8 pa, v0, v1;
    #pragma unroll
    for (int j = 0; j < 8; ++j) pa[j] = (short)f2bf(pv[j]);
    #pragma unroll
    for (int j = 0; j < 4; ++j){
      const float* vp = &base[(size_t)(q0w + g*4 + j)*768 + 512 + hoff];
      v0[j] = (short)f2bf(vp[r]);
      v1[j] = (short)f2bf(vp[r + 16]);
      v0[j+4] = 0; v1[j+4] = 0;
    }
    O0 = __builtin_amdgcn_mfma_f32_16x16x32_bf16(pa, v0, O0, 0,0,0);
    O1 = __builtin_amdgcn_mfma_f32_16x16x32_bf16(pa, v1, O1, 0,0,0);
  }

  float inv = 1.f / l;
  if (lane < 16) cbuf[wv][lane] = inv;
  asm volatile("s_waitcnt lgkmcnt(0)" ::: "memory");
  f32x4 iv = *(const f32x4*)&cbuf[wv][g*4];
  if constexpr (OPL==0){
    float* op = o + ((size_t)b*1024 + q0w + g*4)*256 + hoff;
    #pragma unroll
    for (int j = 0; j < 4; ++j){
      op[(size_t)j*256 + r]      = O0[j] * iv[j];
      op[(size_t)j*256 + r + 16] = O1[j] * iv[j];
    }
  } else {
    size_t ob = ((size_t)b*1024 + q0w + g*4)*256 + hoff;
    #pragma unroll
    for (int j = 0; j < 4; ++j){
      unsigned short hh, ll;
      tsplit(O0[j]*iv[j], hh, ll);
      oh[ob + (size_t)j*256 + r] = hh;  ol[ob + (size_t)j*256 + r] = ll;
      tsplit(O1[j]*iv[j], hh, ll);
      oh[ob + (size_t)j*256 + r + 16] = hh;  ol[ob + (size_t)j*256 + r + 16] = ll;
    }
  }
}

// ---------------------------------------------------------------- launch
extern "C" void kernel_launch(void* const* d_in, const int* in_sizes, int n_in,
                              void* d_out, int out_size, void* d_ws, size_t ws_size,
                              hipStream_t stream)
{
  (void)in_sizes; (void)n_in; (void)out_size;
  const float* xc   = (const float*)d_in[0];
  const float* yc   = (const float*)d_in[1];
  const float* xt   = (const float*)d_in[2];
  const float* eW1  = (const float*)d_in[3];
  const float* eb1  = (const float*)d_in[4];
  const float* eW2  = (const float*)d_in[5];
  const float* eb2  = (const float*)d_in[6];
  const float* Wqkv = (const float*)d_in[7];
  const float* bqkv = (const float*)d_in[8];
  const float* Wo   = (const float*)d_in[9];
  const float* bo   = (const float*)d_in[10];
  const float* ln1g = (const float*)d_in[11];
  const float* ln1b = (const float*)d_in[12];
  const float* ln2g = (const float*)d_in[13];
  const float* ln2b = (const float*)d_in[14];
  const float* Wff1 = (const float*)d_in[15];
  const float* bff1 = (const float*)d_in[16];
  const float* Wff2 = (const float*)d_in[17];
  const float* bff2 = (const float*)d_in[18];

  float* zf = (float*)d_out;            // residual stream [8][1024][256] f32 = 8 MB
  char* ws = (char*)d_ws;

  const size_t MiB = 1024*1024;
  const bool hugews = (ws_size == 0) || (ws_size >= 64*MiB);   // observed ws = 256 MiB

  if (hugews){
    unsigned short* lnh = (unsigned short*)ws;                      // 4 MiB
    unsigned short* lnl = lnh + 4*MiB/2;
    float*          scratch = (float*)(ws + 8*MiB);
    unsigned short* ffh_b   = (unsigned short*)scratch;
    unsigned short* W = (unsigned short*)(ws + 32*MiB);
    unsigned short* qkvTh = W;                   // 6*196608 per plane
    unsigned short* qkvTl = W + 1179648;
    unsigned short* woTh  = W + 2359296;         // 6*65536
    unsigned short* woTl  = W + 2752512;
    unsigned short* w1Th  = W + 3145728;         // 6*262144
    unsigned short* w1Tl  = W + 4718592;
    unsigned short* w2Th  = W + 6291456;
    unsigned short* w2Tl  = W + 7864320;
    unsigned short* e2Th  = W + 9437184;         // 65536
    unsigned short* e2Tl  = W + 9502720;
    unsigned short* aoh = (unsigned short*)(ws + 52*MiB);           // 4 MiB
    unsigned short* aol = aoh + 4*MiB/2;

    convt<<<dim3(12,8,6), 256, 0, stream>>>(Wqkv, qkvTh, qkvTl, 256, 768);
    convt<<<dim3(4,8,6),  256, 0, stream>>>(Wo,   woTh,  woTl,  256, 256);
    convt<<<dim3(16,8,6), 256, 0, stream>>>(Wff1, w1Th,  w1Tl,  256, 1024);
    convt<<<dim3(4,32,6), 256, 0, stream>>>(Wff2, w2Th,  w2Tl,  1024, 256);
    convt<<<dim3(4,8,1),  256, 0, stream>>>(eW2,  e2Th,  e2Tl,  256, 256);

    encoder_s1<<<8192, 256, 0, stream>>>(xc, yc, xt, eW1, eb1, scratch);
    gemm_mfma<0,1,0,64><<<dim3(4,64), 256, 0, stream>>>(scratch, nullptr, nullptr,
                                                        nullptr, e2Th, e2Tl,
                                                        eb2, nullptr, zf, nullptr, 256, 256);

    for (int l=0; l<6; l++){
      unsigned short* qh_ = qkvTh + (size_t)l*196608;
      unsigned short* ql_ = qkvTl + (size_t)l*196608;
      unsigned short* oh_ = woTh  + (size_t)l*65536;
      unsigned short* olw = woTl  + (size_t)l*65536;
      unsigned short* f1h = w1Th  + (size_t)l*262144;
      unsigned short* f1l = w1Tl  + (size_t)l*262144;
      unsigned short* f2h = w2Th  + (size_t)l*262144;
      unsigned short* f2l = w2Tl  + (size_t)l*262144;

      ln_v2b<<<2048, 256, 0, stream>>>(zf, ln1g+l*256, ln1b+l*256, lnh, lnl);
      gemm_mfma<2,1,0,64><<<dim3(12,64), 256, 0, stream>>>(nullptr, lnh, lnl,
                                                           nullptr, qh_, ql_,
                                                           bqkv+l*768, nullptr, scratch, nullptr, 768, 256);
      attn_v8<1><<<dim3(4,8,8), 1024, 0, stream>>>(scratch, nullptr, aoh, aol);
      gemm_mfma<2,1,2,64><<<dim3(4,64), 256, 0, stream>>>(nullptr, aoh, aol,
                                                          nullptr, oh_, olw,
                                                          bo+l*256, zf, zf, nullptr, 256, 256);
      ln_v2b<<<2048, 256, 0, stream>>>(zf, ln2g+l*256, ln2b+l*256, lnh, lnl);
      gemm_mfma<2,1,3,128><<<dim3(8,64), 256, 0, stream>>>(nullptr, lnh, lnl,
                                                           nullptr, f1h, f1l,
                                                           bff1+l*1024, nullptr, nullptr, ffh_b, 1024, 256);
      gemm_mfma<1,1,2,64><<<dim3(4,64), 256, 0, stream>>>(nullptr, ffh_b, nullptr,
                                                          nullptr, f2h, f2l,
                                                          bff2+l*256, zf, zf, nullptr, 256, 1024);
    }
  } else {
    // conservative fallback: all-f32 path (in-kernel split), chunked scratch
    float* hb      = (float*)(ws);
    float* scratch = (float*)(ws + 8*MiB);
    encoder_s1<<<8192, 256, 0, stream>>>(xc, yc, xt, eW1, eb1, hb);
    gemm_mfma<0,0,0,128><<<dim3(2,64), 256, 0, stream>>>(hb, nullptr, nullptr, eW2, nullptr, nullptr,
                                                         eb2, nullptr, zf, nullptr, 256, 256);
    for (int l=0; l<6; l++){
      const float* Wq = Wqkv + (size_t)l*256*768;
      const float* Wl = Wo   + (size_t)l*256*256;
      const float* W1 = Wff1 + (size_t)l*256*1024;
      const float* W2 = Wff2 + (size_t)l*1024*256;

      ln_v2<<<2048, 256, 0, stream>>>(zf, ln1g+l*256, ln1b+l*256, hb);
      for (int c=0; c<4; c++){
        float* hrows = hb + (size_t)c*2048*256;
        gemm_mfma<0,0,0,128><<<dim3(6,16), 256, 0, stream>>>(hrows, nullptr, nullptr, Wq, nullptr, nullptr,
                                                             bqkv+l*768, nullptr, scratch, nullptr, 768, 256);
        attn_v8<0><<<dim3(4,8,2), 1024, 0, stream>>>(scratch, hrows, nullptr, nullptr);
      }
      gemm_mfma<0,0,2,128><<<dim3(2,64), 256, 0, stream>>>(hb, nullptr, nullptr, Wl, nullptr, nullptr,
                                                           bo+l*256, zf, zf, nullptr, 256, 256);
      ln_v2<<<2048, 256, 0, stream>>>(zf, ln2g+l*256, ln2b+l*256, hb);
      for (int c=0; c<4; c++){
        float* hrows = hb + (size_t)c*2048*256;
        float* zrows = zf + (size_t)c*2048*256;
        gemm_mfma<0,0,1,128><<<dim3(8,16), 256, 0, stream>>>(hrows, nullptr, nullptr, W1, nullptr, nullptr,
                                                             bff1+l*1024, nullptr, scratch, nullptr, 1024, 256);
        gemm_mfma<0,0,2,128><<<dim3(2,16), 256, 0, stream>>>(scratch, nullptr, nullptr, W2, nullptr, nullptr,
                                                             bff2+l*256, zrows, zrows, nullptr, 256, 1024);
      }
    }
  }
}